// Round 2
// baseline (1994.132 us; speedup 1.0000x reference)
//
#include <hip/hip_runtime.h>
#include <cstdint>
#include <math.h>

typedef unsigned int u32;
typedef unsigned long long u64;

// ---------------- geometry ----------------
#define N_BATCH 8
#define C_IN    512
#define PX      2500     // 50*50
#define KDIM    4608     // 512*9
#define KHALF   2304
#define NA      22500
#define PRE_NMS 6000
#define POST_NMS 300

// d_out float layout (reference tuple concatenated):
// rpn_locs   [8][22500][4]  @ 0        (720000)
// rpn_scores [8][22500][2]  @ 720000   (360000)
// anchors    [22500][4]     @ 1080000  (90000)
// rois       [300][4]       @ 1170000  (1200)
#define OUT_SCORES 720000
#define OUT_ANCH   1080000
#define OUT_ROIS   1170000

// ws layout (float offsets)
#define WS_X     0            // x: 8*512*2500 = 10,240,000 floats (pre-relu conv+bias)
#define WS_SCORE 10240000     // 22500
#define WS_BOX   10262500     // 22500*4
#define WS_LIST  10352500     // u64[6000] (12000 floats, 8B aligned)
#define WS_CAND  10364500     // 6000*4
#define WS_META  10388500     // ints

// =================== conv3x3 + bias (implicit GEMM, K-split=2, atomic accumulate) ===================
// tile: 128 co x 128 px x K=2304, KB=32, 256 threads, 8x8 register tile
// grid = 4 co-tiles * 20 px-tiles * 8 n * 2 ksplit = 1280 blocks (exactly 5/CU)
// LDS = 2 * 32*128*4 = 32768 B -> 5 blocks/CU resident
__global__ __launch_bounds__(256) void k_conv3(const float* __restrict__ in,
                                               const float* __restrict__ Wc,
                                               const float* __restrict__ bc,
                                               float* __restrict__ xout) {
    __shared__ float As[32][128];
    __shared__ float Bs[32][128];
    int b  = blockIdx.x;
    int cb = b & 3;            // co tile (4)
    int pt = (b >> 2) % 20;    // px tile (20)
    int r  = (b >> 2) / 20;    // 0..15
    int n     = r >> 1;
    int split = r & 1;
    int t  = threadIdx.x;
    int tx = t & 15, ty = t >> 4;
    int px0 = pt * 128, co0 = cb * 128;
    const float* inN = in + (size_t)n * C_IN * PX;

    float acc[8][8];
#pragma unroll
    for (int i = 0; i < 8; ++i)
#pragma unroll
        for (int j = 0; j < 8; ++j) acc[i][j] = 0.f;

    int k0beg = split * KHALF;
    for (int k0 = k0beg; k0 < k0beg + KHALF; k0 += 32) {
        // A: W[co0..co0+128][k0..k0+32]  (thread: co=t>>1, 16 k's)
        {
            int co  = t >> 1;
            int kkb = (t & 1) << 4;
            const float* wp = Wc + (size_t)(co0 + co) * KDIM + k0 + kkb;
#pragma unroll
            for (int q = 0; q < 4; ++q) {
                float4 w = *(const float4*)(wp + q * 4);
                As[kkb + q * 4 + 0][co] = w.x;
                As[kkb + q * 4 + 1][co] = w.y;
                As[kkb + q * 4 + 2][co] = w.z;
                As[kkb + q * 4 + 3][co] = w.w;
            }
        }
        // B: im2col gather [32 k][128 px]
        {
            int pxl = t & 127;
            int kk0 = (t >> 7) << 4;
            int px  = px0 + pxl;
            int y   = px / 50, x = px - y * 50;
#pragma unroll
            for (int it = 0; it < 16; ++it) {
                int kk = kk0 + it;
                int k  = k0 + kk;
                int ci = k / 9;
                int rr = k - ci * 9;
                int ky = rr / 3;
                int kx = rr - ky * 3;
                float v = 0.f;
                if (px < PX) {
                    int iy = y + ky - 1, ix = x + kx - 1;
                    if ((unsigned)iy < 50u && (unsigned)ix < 50u)
                        v = inN[ci * PX + iy * 50 + ix];
                }
                Bs[kk][pxl] = v;
            }
        }
        __syncthreads();
#pragma unroll 8
        for (int kk = 0; kk < 32; ++kk) {
            float a[8], bb[8];
            *(float4*)&a[0]  = *(const float4*)&As[kk][ty * 8];
            *(float4*)&a[4]  = *(const float4*)&As[kk][ty * 8 + 4];
            *(float4*)&bb[0] = *(const float4*)&Bs[kk][tx * 8];
            *(float4*)&bb[4] = *(const float4*)&Bs[kk][tx * 8 + 4];
#pragma unroll
            for (int i = 0; i < 8; ++i)
#pragma unroll
                for (int j = 0; j < 8; ++j)
                    acc[i][j] = fmaf(a[i], bb[j], acc[i][j]);
        }
        __syncthreads();
    }
    // atomic accumulate partial (+bias from split 0). x was zeroed this launch;
    // exactly two commutative fp32 adds per element -> deterministic.
    int pxb = px0 + tx * 8;
#pragma unroll
    for (int i = 0; i < 8; ++i) {
        int co = co0 + ty * 8 + i;
        float bias = (split == 0) ? bc[co] : 0.f;
        float* dst = xout + ((size_t)n * C_IN + co) * PX;
#pragma unroll
        for (int j = 0; j < 8; ++j) {
            int px = pxb + j;
            if (px < PX) atomicAdd(&dst[px], acc[i][j] + bias);
        }
    }
}

// =================== 1x1 heads: 54(=36 reg + 18 cls) x 512 GEMM ===================
// reads pre-relu x, applies relu at load. tile: 64 co x 128 px, KB=32
__global__ __launch_bounds__(256) void k_heads(const float* __restrict__ x,
                                               const float* __restrict__ Wreg,
                                               const float* __restrict__ breg,
                                               const float* __restrict__ Wcls,
                                               const float* __restrict__ bcls,
                                               float* __restrict__ out) {
    __shared__ float As[32][68];
    __shared__ float Bs[32][132];
    int b  = blockIdx.x;
    int pt = b % 20, n = b / 20;
    int t  = threadIdx.x;
    int tx = t & 15, ty = t >> 4;
    int px0 = pt * 128;
    float acc[4][8];
#pragma unroll
    for (int i = 0; i < 4; ++i)
#pragma unroll
        for (int j = 0; j < 8; ++j) acc[i][j] = 0.f;

    for (int k0 = 0; k0 < 512; k0 += 32) {
        {
            int c   = t >> 2;
            int kkb = (t & 3) << 3;
            const float* src = nullptr;
            if (c < 36)      src = Wreg + (size_t)c * 512 + k0 + kkb;
            else if (c < 54) src = Wcls + (size_t)(c - 36) * 512 + k0 + kkb;
#pragma unroll
            for (int q = 0; q < 2; ++q) {
                float4 w = src ? *(const float4*)(src + q * 4) : make_float4(0, 0, 0, 0);
                As[kkb + q * 4 + 0][c] = w.x;
                As[kkb + q * 4 + 1][c] = w.y;
                As[kkb + q * 4 + 2][c] = w.z;
                As[kkb + q * 4 + 3][c] = w.w;
            }
        }
        {
            int pxl = t & 127;
            int kk0 = (t >> 7) << 4;
            int px  = px0 + pxl;
#pragma unroll
            for (int it = 0; it < 16; ++it) {
                int kk = kk0 + it;
                float v = 0.f;
                if (px < PX) v = fmaxf(x[((size_t)n * 512 + k0 + kk) * PX + px], 0.f);
                Bs[kk][pxl] = v;
            }
        }
        __syncthreads();
#pragma unroll 8
        for (int kk = 0; kk < 32; ++kk) {
            float a[4], bb[8];
            *(float4*)&a[0]  = *(const float4*)&As[kk][ty * 4];
            *(float4*)&bb[0] = *(const float4*)&Bs[kk][tx * 8];
            *(float4*)&bb[4] = *(const float4*)&Bs[kk][tx * 8 + 4];
#pragma unroll
            for (int i = 0; i < 4; ++i)
#pragma unroll
                for (int j = 0; j < 8; ++j)
                    acc[i][j] = fmaf(a[i], bb[j], acc[i][j]);
        }
        __syncthreads();
    }
    int pxb = px0 + tx * 8;
#pragma unroll
    for (int i = 0; i < 4; ++i) {
        int c = ty * 4 + i;
        if (c >= 54) continue;
        float bias = (c < 36) ? breg[c] : bcls[c - 36];
        for (int j = 0; j < 8; ++j) {
            int px = pxb + j;
            if (px >= PX) break;
            float v = acc[i][j] + bias;
            if (c < 36)
                out[(size_t)n * 90000 + (size_t)px * 36 + c] = v;
            else
                out[OUT_SCORES + (size_t)n * 45000 + (size_t)px * 18 + (c - 36)] = v;
        }
    }
}

// =================== anchors + decode (batch 0) ===================
__device__ inline float readDim(const void* p) {
    int v = *(const int*)p;
    if (v > 0 && v <= 100000) return (float)v;
    return *(const float*)p;
}

__global__ __launch_bounds__(256) void k_decode(float* __restrict__ dout,
                                                float* __restrict__ ws,
                                                const void* pih, const void* piw) {
    int idx = blockIdx.x * 256 + threadIdx.x;
    if (idx >= NA) return;
    float imgH = readDim(pih), imgW = readDim(piw);
    int a  = idx % 9;
    int px = idx / 9;
    int y = px / 50, x = px - y * 50;
    const float ratios[3] = {0.5f, 1.f, 2.f};
    const float scales[3] = {8.f, 16.f, 32.f};
    float r = ratios[a / 3], s = scales[a % 3];
    float hh = 16.f * s * sqrtf(r);
    float wv = 16.f * s * sqrtf(1.f / r);
    float ay1 = y * 16.f + 8.f - 0.5f * hh;
    float ax1 = x * 16.f + 8.f - 0.5f * wv;
    float ay2 = y * 16.f + 8.f + 0.5f * hh;
    float ax2 = x * 16.f + 8.f + 0.5f * wv;
    *(float4*)(dout + OUT_ANCH + (size_t)idx * 4) = make_float4(ay1, ax1, ay2, ax2);

    // decode batch 0
    float4 loc = *(const float4*)(dout + (size_t)idx * 4);
    float s0 = dout[OUT_SCORES + (size_t)idx * 2];
    float s1 = dout[OUT_SCORES + (size_t)idx * 2 + 1];
    float fg = 1.f / (1.f + expf(s0 - s1));
    float ah = ay2 - ay1, aw = ax2 - ax1;
    float acy = ay1 + 0.5f * ah, acx = ax1 + 0.5f * aw;
    float cy = loc.x * ah + acy;
    float cx = loc.y * aw + acx;
    float bh = expf(loc.z) * ah;
    float bw = expf(loc.w) * aw;
    float b0 = cy - 0.5f * bh, b1 = cx - 0.5f * bw;
    float b2 = cy + 0.5f * bh, b3 = cx + 0.5f * bw;
    b0 = fminf(fmaxf(b0, 0.f), imgH);
    b1 = fminf(fmaxf(b1, 0.f), imgW);
    b2 = fminf(fmaxf(b2, 0.f), imgH);
    b3 = fminf(fmaxf(b3, 0.f), imgW);
    bool valid = ((b2 - b0) >= 16.f) && ((b3 - b1) >= 16.f);
    ws[WS_SCORE + idx] = valid ? fg : -INFINITY;
    *(float4*)(ws + WS_BOX + (size_t)idx * 4) = make_float4(b0, b1, b2, b3);
}

// =================== top-6000 threshold + compaction (single block) ===================
__device__ inline u32 fkey(float s) {
    u32 u = __float_as_uint(s);
    return (u & 0x80000000u) ? ~u : (u | 0x80000000u);
}

__global__ __launch_bounds__(1024) void k_select(const float* __restrict__ score,
                                                 u64* __restrict__ list,
                                                 int* __restrict__ meta) {
    __shared__ u32 hist[4096];
    __shared__ int sB1, sB2, sB3, sM3, sNeed, sV;
    __shared__ u32 sT32;
    __shared__ int cHi, cTie;
    int t = threadIdx.x;
    const int NT = 1024;

    // ---- pass 1: top 12 bits ----
    for (int i = t; i < 4096; i += NT) hist[i] = 0;
    __syncthreads();
    for (int i = t; i < NA; i += NT) atomicAdd(&hist[fkey(score[i]) >> 20], 1u);
    __syncthreads();
    for (int off = 1; off < 4096; off <<= 1) {
        u32 v[4]; int c = 0;
        for (int bb = t; bb < 4096; bb += NT) { v[c++] = hist[bb] + ((bb + off < 4096) ? hist[bb + off] : 0u); }
        __syncthreads();
        c = 0;
        for (int bb = t; bb < 4096; bb += NT) hist[bb] = v[c++];
        __syncthreads();
    }
    for (int bb = t; bb < 4096; bb += NT) {
        u32 Sb  = hist[bb];
        u32 Sb1 = (bb < 4095) ? hist[bb + 1] : 0u;
        if (Sb >= PRE_NMS && Sb1 < PRE_NMS) sB1 = bb;
    }
    if (t == 0) sV = (int)hist[2048];   // count of finite (positive-float-key) scores
    __syncthreads();
    int B1 = sB1;
    int m1 = (B1 < 4095) ? (int)hist[B1 + 1] : 0;
    int V  = sV;
    __syncthreads();

    // ---- pass 2: mid 12 bits within bin B1 ----
    for (int i = t; i < 4096; i += NT) hist[i] = 0;
    __syncthreads();
    for (int i = t; i < NA; i += NT) {
        u32 key = fkey(score[i]);
        if ((int)(key >> 20) == B1) atomicAdd(&hist[(key >> 8) & 0xFFFu], 1u);
    }
    __syncthreads();
    for (int off = 1; off < 4096; off <<= 1) {
        u32 v[4]; int c = 0;
        for (int bb = t; bb < 4096; bb += NT) { v[c++] = hist[bb] + ((bb + off < 4096) ? hist[bb + off] : 0u); }
        __syncthreads();
        c = 0;
        for (int bb = t; bb < 4096; bb += NT) hist[bb] = v[c++];
        __syncthreads();
    }
    for (int bb = t; bb < 4096; bb += NT) {
        int Sb  = m1 + (int)hist[bb];
        int Sb1 = m1 + (int)((bb < 4095) ? hist[bb + 1] : 0u);
        if (Sb >= PRE_NMS && Sb1 < PRE_NMS) sB2 = bb;
    }
    __syncthreads();
    int B2 = sB2;
    int m2 = m1 + (int)((B2 < 4095) ? hist[B2 + 1] : 0u);
    u32 P24 = ((u32)B1 << 12) | (u32)B2;
    __syncthreads();

    // ---- pass 3: low 8 bits within 24-bit prefix ----
    for (int i = t; i < 256; i += NT) hist[i] = 0;
    __syncthreads();
    for (int i = t; i < NA; i += NT) {
        u32 key = fkey(score[i]);
        if ((key >> 8) == P24) atomicAdd(&hist[key & 0xFFu], 1u);
    }
    __syncthreads();
    for (int off = 1; off < 256; off <<= 1) {
        u32 v[1]; int c = 0;
        for (int bb = t; bb < 256; bb += NT) { v[c++] = hist[bb] + ((bb + off < 256) ? hist[bb + off] : 0u); }
        __syncthreads();
        c = 0;
        for (int bb = t; bb < 256; bb += NT) hist[bb] = v[c++];
        __syncthreads();
    }
    for (int bb = t; bb < 256; bb += NT) {
        int Sb  = m2 + (int)hist[bb];
        int Sb1 = m2 + (int)((bb < 255) ? hist[bb + 1] : 0u);
        if (Sb >= PRE_NMS && Sb1 < PRE_NMS) {
            sB3   = bb;
            sM3   = m2 + (int)((bb < 255) ? hist[bb + 1] : 0u);
            sNeed = PRE_NMS - sM3;
            sT32  = (P24 << 8) | (u32)bb;
        }
    }
    if (t == 0) { cHi = 0; cTie = 0; meta[0] = (V < PRE_NMS) ? V : PRE_NMS; }
    __syncthreads();
    int m3 = sM3, need = sNeed;
    u32 T32 = sT32;

    // ---- compaction: exactly 6000 entries ----
    for (int i = t; i < NA; i += NT) {
        u32 key = fkey(score[i]);
        u64 comp = ((u64)key << 32) | (u64)(0xFFFFFFFFu - (u32)i);
        if (key > T32) {
            int p = atomicAdd(&cHi, 1);
            list[p] = comp;
        } else if (key == T32) {
            int p = atomicAdd(&cTie, 1);
            if (p < need) list[m3 + p] = comp;
        }
    }
}

// =================== bitonic sort 8192 (desc) + gather cand boxes ===================
__global__ __launch_bounds__(1024) void k_sort(u64* __restrict__ list,
                                               const float* __restrict__ boxes,
                                               float* __restrict__ cand) {
    __shared__ u64 sb[8192];
    int t = threadIdx.x;
    for (int i = t; i < 8192; i += 1024) sb[i] = (i < PRE_NMS) ? list[i] : 0ull;
    __syncthreads();
    for (int k = 2; k <= 8192; k <<= 1) {
        for (int j = k >> 1; j > 0; j >>= 1) {
            for (int i = t; i < 8192; i += 1024) {
                int ixj = i ^ j;
                if (ixj > i) {
                    u64 a = sb[i], b = sb[ixj];
                    bool desc = ((i & k) == 0);
                    if (desc ? (a < b) : (a > b)) { sb[i] = b; sb[ixj] = a; }
                }
            }
            __syncthreads();
        }
    }
    for (int e = t; e < PRE_NMS; e += 1024) {
        u32 idx = 0xFFFFFFFFu - (u32)sb[e];
        float4 bx = *(const float4*)(boxes + (size_t)idx * 4);
        *(float4*)(cand + (size_t)e * 4) = bx;
    }
}

// =================== greedy NMS, early-exit at 300 survivors ===================
__global__ __launch_bounds__(256) void k_nms(const float* __restrict__ cand,
                                             const int* __restrict__ meta,
                                             float* __restrict__ rois) {
    __shared__ float kb[POST_NMS][4];
    __shared__ u64 supArr[4];
    int t = threadIdx.x;
    int lane = t & 63, wid = t >> 6;
    int keepN = meta[0];
    int kept = 0;

    for (int c0 = 0; c0 < PRE_NMS && kept < POST_NMS; c0 += 64) {
        int i = c0 + lane;
        float y1 = 0, x1 = 0, y2 = 0, x2 = 0;
        bool elig = (i < keepN);
        if (i < PRE_NMS) {
            float4 bx = *(const float4*)(cand + (size_t)i * 4);
            y1 = bx.x; x1 = bx.y; y2 = bx.z; x2 = bx.w;
        } else {
            elig = false;
        }
        float area = (y2 - y1) * (x2 - x1);

        // phase A: vs already-kept boxes, kept-list split across 4 waves
        bool supA = false;
        for (int jj = wid; jj < kept; jj += 4) {
            float ky1 = kb[jj][0], kx1 = kb[jj][1], ky2 = kb[jj][2], kx2 = kb[jj][3];
            float yy1 = fmaxf(ky1, y1), xx1 = fmaxf(kx1, x1);
            float yy2 = fminf(ky2, y2), xx2 = fminf(kx2, x2);
            float inter = fmaxf(yy2 - yy1, 0.f) * fmaxf(xx2 - xx1, 0.f);
            float karea = (ky2 - ky1) * (kx2 - kx1);
            float iou = inter / (karea + area - inter + 1e-12f);
            if (iou > 0.7f) { supA = true; break; }
        }
        supArr[wid] = __ballot(supA);
        __syncthreads();
        u64 sup = supArr[0] | supArr[1] | supArr[2] | supArr[3];
        u64 eligMask = __ballot(elig);

        // phase B: within-chunk greedy (all 4 waves compute identically)
        for (int s = 0; s < 64; ++s) {
            if (kept >= POST_NMS) break;
            if (!((eligMask >> s) & 1ull)) continue;
            if ((sup >> s) & 1ull) continue;
            // box s is kept
            float sy1 = __shfl(y1, s), sx1 = __shfl(x1, s);
            float sy2 = __shfl(y2, s), sx2 = __shfl(x2, s);
            float sar = __shfl(area, s);
            if (wid == 0 && lane == s) {
                kb[kept][0] = y1; kb[kept][1] = x1; kb[kept][2] = y2; kb[kept][3] = x2;
                *(float4*)(rois + (size_t)kept * 4) = make_float4(y1, x1, y2, x2);
            }
            float yy1 = fmaxf(sy1, y1), xx1 = fmaxf(sx1, x1);
            float yy2 = fminf(sy2, y2), xx2 = fminf(sx2, x2);
            float inter = fmaxf(yy2 - yy1, 0.f) * fmaxf(xx2 - xx1, 0.f);
            float iou = inter / (sar + area - inter + 1e-12f);
            bool kill = (lane > s) && (iou > 0.7f);
            sup |= __ballot(kill);
            kept++;
        }
        __syncthreads();
    }
    // zero-fill remaining rois
    for (int r = kept * 4 + t; r < POST_NMS * 4; r += 256) rois[r] = 0.f;
}

// =================== launcher ===================
extern "C" void kernel_launch(void* const* d_in, const int* in_sizes, int n_in,
                              void* d_out, int out_size, void* d_ws, size_t ws_size,
                              hipStream_t stream) {
    const float* feat = (const float*)d_in[0];
    const float* Wc   = (const float*)d_in[1];
    const float* bc   = (const float*)d_in[2];
    const float* Wcls = (const float*)d_in[3];
    const float* bcls = (const float*)d_in[4];
    const float* Wreg = (const float*)d_in[5];
    const float* breg = (const float*)d_in[6];
    const void* pih   = d_in[7];
    const void* piw   = d_in[8];
    float* out = (float*)d_out;
    float* ws  = (float*)d_ws;

    u64* list = (u64*)(ws + WS_LIST);
    int* meta = (int*)(ws + WS_META);

    // zero the conv accumulator (atomicAdd target) every launch
    hipMemsetAsync(ws + WS_X, 0, (size_t)N_BATCH * C_IN * PX * sizeof(float), stream);

    hipLaunchKernelGGL(k_conv3, dim3(1280), dim3(256), 0, stream, feat, Wc, bc, ws + WS_X);
    hipLaunchKernelGGL(k_heads, dim3(160), dim3(256), 0, stream, ws + WS_X, Wreg, breg, Wcls, bcls, out);
    hipLaunchKernelGGL(k_decode, dim3(88), dim3(256), 0, stream, out, ws, pih, piw);
    hipLaunchKernelGGL(k_select, dim3(1), dim3(1024), 0, stream, ws + WS_SCORE, list, meta);
    hipLaunchKernelGGL(k_sort, dim3(1), dim3(1024), 0, stream, list, ws + WS_BOX, ws + WS_CAND);
    hipLaunchKernelGGL(k_nms, dim3(1), dim3(256), 0, stream, ws + WS_CAND, meta, out + OUT_ROIS);
}

// Round 3
// 985.938 us; speedup vs baseline: 2.0226x; 2.0226x over previous
//
#include <hip/hip_runtime.h>
#include <cstdint>
#include <math.h>

typedef unsigned int u32;
typedef unsigned long long u64;
typedef __attribute__((ext_vector_type(8))) short short8v;   // 8 bf16 (4 VGPR)
typedef __attribute__((ext_vector_type(4))) float f32x4;     // MFMA acc

// ---------------- geometry ----------------
#define N_BATCH 8
#define C_IN    512
#define PX      2500     // 50*50
#define KDIM    4608     // 512*9
#define NA      22500
#define PRE_NMS 6000
#define POST_NMS 300

// d_out float layout (reference tuple concatenated):
// rpn_locs   [8][22500][4]  @ 0        (720000)
// rpn_scores [8][22500][2]  @ 720000   (360000)
// anchors    [22500][4]     @ 1080000  (90000)
// rois       [300][4]       @ 1170000  (1200)
#define OUT_SCORES 720000
#define OUT_ANCH   1080000
#define OUT_ROIS   1170000

// ws layout (float offsets)
#define WS_X     0            // x: 8*512*2500 floats (post-relu conv out)
#define WS_SCORE 10240000     // 22500
#define WS_BOX   10262500     // 22500*4
#define WS_LIST  10352500     // u64[6000]
#define WS_CAND  10364500     // 6000*4
#define WS_META  10388500     // ints

// ---------- bf16 split helpers ----------
__device__ inline unsigned short f2bf(float f) {
    u32 u = __float_as_uint(f);
    u32 r = (u + 0x7FFFu + ((u >> 16) & 1u)) >> 16;   // RNE
    return (unsigned short)r;
}
__device__ inline float bf2f(unsigned short h) {
    return __uint_as_float((u32)h << 16);
}

// =================== conv3x3 + bias + relu : bf16x3-split MFMA implicit GEMM ===================
// block tile 128co x 128px, BK=32 fp32-k; 4 waves, each 64x64 (4x4 frags of 16x16x32)
// grid = 4 co-tiles * 20 px-tiles * 8 n = 640
__global__ __launch_bounds__(256) void k_conv3(const float* __restrict__ in,
                                               const float* __restrict__ Wc,
                                               const float* __restrict__ bc,
                                               float* __restrict__ xout) {
    __shared__ unsigned short AsH[128][40];   // [co][k] hi
    __shared__ unsigned short AsL[128][40];   // [co][k] lo
    __shared__ unsigned short BsH[128][40];   // [px][k] hi
    __shared__ unsigned short BsL[128][40];   // [px][k] lo

    int b  = blockIdx.x;
    int cb = b & 3;
    int pt = (b >> 2) % 20;
    int n  = (b >> 2) / 20;
    int t  = threadIdx.x;
    int lane = t & 63;
    int w  = t >> 6;
    int wr = w >> 1, wc = w & 1;          // wave -> (co half, px half)
    int px0 = pt * 128, co0 = cb * 128;
    const float* inN = in + (size_t)n * C_IN * PX;

    // staging roles
    int sco = t >> 1;                 // A: co 0..127
    int skb = (t & 1) << 4;           // A: k offset 0/16
    int spx = t & 127;                // B: px 0..127
    int skk = (t >> 7) << 4;          // B: k offset 0/16
    int gpx = px0 + spx;
    int sy  = gpx / 50;
    int sx  = gpx - sy * 50;
    bool pxok = (gpx < PX);

    f32x4 acc[4][4];
#pragma unroll
    for (int i = 0; i < 4; ++i)
#pragma unroll
        for (int j = 0; j < 4; ++j) acc[i][j] = (f32x4)0.f;

    const int ro = lane & 15;
    const int g8 = (lane >> 4) << 3;          // k offset within 32: 0/8/16/24

    for (int k0 = 0; k0 < KDIM; k0 += 32) {
        // ---- stage A: weights 128co x 32k, split hi/lo ----
        {
            const float* wp = Wc + (size_t)(co0 + sco) * KDIM + k0 + skb;
            unsigned short hh[16], ll[16];
#pragma unroll
            for (int q = 0; q < 4; ++q) {
                float4 wv = *(const float4*)(wp + q * 4);
                float fv0 = wv.x, fv1 = wv.y, fv2 = wv.z, fv3 = wv.w;
                unsigned short h0 = f2bf(fv0), h1 = f2bf(fv1), h2 = f2bf(fv2), h3 = f2bf(fv3);
                hh[q*4+0] = h0; ll[q*4+0] = f2bf(fv0 - bf2f(h0));
                hh[q*4+1] = h1; ll[q*4+1] = f2bf(fv1 - bf2f(h1));
                hh[q*4+2] = h2; ll[q*4+2] = f2bf(fv2 - bf2f(h2));
                hh[q*4+3] = h3; ll[q*4+3] = f2bf(fv3 - bf2f(h3));
            }
            short8v v0, v1, u0, u1;
#pragma unroll
            for (int e = 0; e < 8; ++e) {
                v0[e] = (short)hh[e]; v1[e] = (short)hh[8 + e];
                u0[e] = (short)ll[e]; u1[e] = (short)ll[8 + e];
            }
            *(short8v*)&AsH[sco][skb]     = v0;
            *(short8v*)&AsH[sco][skb + 8] = v1;
            *(short8v*)&AsL[sco][skb]     = u0;
            *(short8v*)&AsL[sco][skb + 8] = u1;
        }
        // ---- stage B: im2col 128px x 32k, split hi/lo ----
        {
            int k  = k0 + skk;
            int ci = k / 9;
            int r  = k - ci * 9;
            unsigned short hh[16], ll[16];
#pragma unroll
            for (int it = 0; it < 16; ++it) {
                int ky = (r * 11) >> 5;        // r/3 for r<9
                int kx = r - ky * 3;
                float v = 0.f;
                if (pxok) {
                    int iy = sy + ky - 1, ix = sx + kx - 1;
                    if ((unsigned)iy < 50u && (unsigned)ix < 50u)
                        v = inN[ci * PX + iy * 50 + ix];
                }
                unsigned short hs = f2bf(v);
                hh[it] = hs;
                ll[it] = f2bf(v - bf2f(hs));
                if (++r == 9) { r = 0; ++ci; }
            }
            short8v v0, v1, u0, u1;
#pragma unroll
            for (int e = 0; e < 8; ++e) {
                v0[e] = (short)hh[e]; v1[e] = (short)hh[8 + e];
                u0[e] = (short)ll[e]; u1[e] = (short)ll[8 + e];
            }
            *(short8v*)&BsH[spx][skk]     = v0;
            *(short8v*)&BsH[spx][skk + 8] = v1;
            *(short8v*)&BsL[spx][skk]     = u0;
            *(short8v*)&BsL[spx][skk + 8] = u1;
        }
        __syncthreads();

        // ---- fragments + 3-pass MFMA ----
        short8v aH[4], aL[4], bH[4], bL[4];
#pragma unroll
        for (int s = 0; s < 4; ++s) {
            aH[s] = *(const short8v*)&AsH[wr * 64 + s * 16 + ro][g8];
            aL[s] = *(const short8v*)&AsL[wr * 64 + s * 16 + ro][g8];
            bH[s] = *(const short8v*)&BsH[wc * 64 + s * 16 + ro][g8];
            bL[s] = *(const short8v*)&BsL[wc * 64 + s * 16 + ro][g8];
        }
#pragma unroll
        for (int i = 0; i < 4; ++i)
#pragma unroll
            for (int j = 0; j < 4; ++j) {
                acc[i][j] = __builtin_amdgcn_mfma_f32_16x16x32_bf16(aH[i], bH[j], acc[i][j], 0, 0, 0);
                acc[i][j] = __builtin_amdgcn_mfma_f32_16x16x32_bf16(aH[i], bL[j], acc[i][j], 0, 0, 0);
                acc[i][j] = __builtin_amdgcn_mfma_f32_16x16x32_bf16(aL[i], bH[j], acc[i][j], 0, 0, 0);
            }
        __syncthreads();
    }

    // ---- epilogue: bias + relu, fp32 store ----
    int coB  = co0 + wr * 64;
    int pxB  = px0 + wc * 64 + ro;
    int rowg = (lane >> 4) << 2;
#pragma unroll
    for (int i = 0; i < 4; ++i) {
#pragma unroll
        for (int rg = 0; rg < 4; ++rg) {
            int co = coB + i * 16 + rowg + rg;
            float bias = bc[co];
            float* dst = xout + ((size_t)n * C_IN + co) * PX;
#pragma unroll
            for (int j = 0; j < 4; ++j) {
                int px = pxB + j * 16;
                if (px < PX) dst[px] = fmaxf(acc[i][j][rg] + bias, 0.f);
            }
        }
    }
}

// =================== 1x1 heads: 54(=36 reg + 18 cls) x 512 GEMM (fp32 VALU) ===================
__global__ __launch_bounds__(256) void k_heads(const float* __restrict__ x,
                                               const float* __restrict__ Wreg,
                                               const float* __restrict__ breg,
                                               const float* __restrict__ Wcls,
                                               const float* __restrict__ bcls,
                                               float* __restrict__ out) {
    __shared__ float As[32][68];
    __shared__ float Bs[32][132];
    int b  = blockIdx.x;
    int pt = b % 20, n = b / 20;
    int t  = threadIdx.x;
    int tx = t & 15, ty = t >> 4;
    int px0 = pt * 128;
    float acc[4][8];
#pragma unroll
    for (int i = 0; i < 4; ++i)
#pragma unroll
        for (int j = 0; j < 8; ++j) acc[i][j] = 0.f;

    for (int k0 = 0; k0 < 512; k0 += 32) {
        {
            int c   = t >> 2;
            int kkb = (t & 3) << 3;
            const float* src = nullptr;
            if (c < 36)      src = Wreg + (size_t)c * 512 + k0 + kkb;
            else if (c < 54) src = Wcls + (size_t)(c - 36) * 512 + k0 + kkb;
#pragma unroll
            for (int q = 0; q < 2; ++q) {
                float4 w = src ? *(const float4*)(src + q * 4) : make_float4(0, 0, 0, 0);
                As[kkb + q * 4 + 0][c] = w.x;
                As[kkb + q * 4 + 1][c] = w.y;
                As[kkb + q * 4 + 2][c] = w.z;
                As[kkb + q * 4 + 3][c] = w.w;
            }
        }
        {
            int pxl = t & 127;
            int kk0 = (t >> 7) << 4;
            int px  = px0 + pxl;
#pragma unroll
            for (int it = 0; it < 16; ++it) {
                int kk = kk0 + it;
                float v = 0.f;
                if (px < PX) v = fmaxf(x[((size_t)n * 512 + k0 + kk) * PX + px], 0.f);
                Bs[kk][pxl] = v;
            }
        }
        __syncthreads();
#pragma unroll 8
        for (int kk = 0; kk < 32; ++kk) {
            float a[4], bb[8];
            *(float4*)&a[0]  = *(const float4*)&As[kk][ty * 4];
            *(float4*)&bb[0] = *(const float4*)&Bs[kk][tx * 8];
            *(float4*)&bb[4] = *(const float4*)&Bs[kk][tx * 8 + 4];
#pragma unroll
            for (int i = 0; i < 4; ++i)
#pragma unroll
                for (int j = 0; j < 8; ++j)
                    acc[i][j] = fmaf(a[i], bb[j], acc[i][j]);
        }
        __syncthreads();
    }
    int pxb = px0 + tx * 8;
#pragma unroll
    for (int i = 0; i < 4; ++i) {
        int c = ty * 4 + i;
        if (c >= 54) continue;
        float bias = (c < 36) ? breg[c] : bcls[c - 36];
        for (int j = 0; j < 8; ++j) {
            int px = pxb + j;
            if (px >= PX) break;
            float v = acc[i][j] + bias;
            if (c < 36)
                out[(size_t)n * 90000 + (size_t)px * 36 + c] = v;
            else
                out[OUT_SCORES + (size_t)n * 45000 + (size_t)px * 18 + (c - 36)] = v;
        }
    }
}

// =================== anchors + decode (batch 0) ===================
__device__ inline float readDim(const void* p) {
    int v = *(const int*)p;
    if (v > 0 && v <= 100000) return (float)v;
    return *(const float*)p;
}

__global__ __launch_bounds__(256) void k_decode(float* __restrict__ dout,
                                                float* __restrict__ ws,
                                                const void* pih, const void* piw) {
    int idx = blockIdx.x * 256 + threadIdx.x;
    if (idx >= NA) return;
    float imgH = readDim(pih), imgW = readDim(piw);
    int a  = idx % 9;
    int px = idx / 9;
    int y = px / 50, x = px - y * 50;
    const float ratios[3] = {0.5f, 1.f, 2.f};
    const float scales[3] = {8.f, 16.f, 32.f};
    float r = ratios[a / 3], s = scales[a % 3];
    float hh = 16.f * s * sqrtf(r);
    float wv = 16.f * s * sqrtf(1.f / r);
    float ay1 = y * 16.f + 8.f - 0.5f * hh;
    float ax1 = x * 16.f + 8.f - 0.5f * wv;
    float ay2 = y * 16.f + 8.f + 0.5f * hh;
    float ax2 = x * 16.f + 8.f + 0.5f * wv;
    *(float4*)(dout + OUT_ANCH + (size_t)idx * 4) = make_float4(ay1, ax1, ay2, ax2);

    // decode batch 0
    float4 loc = *(const float4*)(dout + (size_t)idx * 4);
    float s0 = dout[OUT_SCORES + (size_t)idx * 2];
    float s1 = dout[OUT_SCORES + (size_t)idx * 2 + 1];
    float fg = 1.f / (1.f + expf(s0 - s1));
    float ah = ay2 - ay1, aw = ax2 - ax1;
    float acy = ay1 + 0.5f * ah, acx = ax1 + 0.5f * aw;
    float cy = loc.x * ah + acy;
    float cx = loc.y * aw + acx;
    float bh = expf(loc.z) * ah;
    float bw = expf(loc.w) * aw;
    float b0 = cy - 0.5f * bh, b1 = cx - 0.5f * bw;
    float b2 = cy + 0.5f * bh, b3 = cx + 0.5f * bw;
    b0 = fminf(fmaxf(b0, 0.f), imgH);
    b1 = fminf(fmaxf(b1, 0.f), imgW);
    b2 = fminf(fmaxf(b2, 0.f), imgH);
    b3 = fminf(fmaxf(b3, 0.f), imgW);
    bool valid = ((b2 - b0) >= 16.f) && ((b3 - b1) >= 16.f);
    ws[WS_SCORE + idx] = valid ? fg : -INFINITY;
    *(float4*)(ws + WS_BOX + (size_t)idx * 4) = make_float4(b0, b1, b2, b3);
}

// =================== top-6000 threshold + compaction (single block) ===================
__device__ inline u32 fkey(float s) {
    u32 u = __float_as_uint(s);
    return (u & 0x80000000u) ? ~u : (u | 0x80000000u);
}

__global__ __launch_bounds__(1024) void k_select(const float* __restrict__ score,
                                                 u64* __restrict__ list,
                                                 int* __restrict__ meta) {
    __shared__ u32 hist[4096];
    __shared__ int sB1, sB2, sB3, sM3, sNeed, sV;
    __shared__ u32 sT32;
    __shared__ int cHi, cTie;
    int t = threadIdx.x;
    const int NT = 1024;

    // ---- pass 1: top 12 bits ----
    for (int i = t; i < 4096; i += NT) hist[i] = 0;
    __syncthreads();
    for (int i = t; i < NA; i += NT) atomicAdd(&hist[fkey(score[i]) >> 20], 1u);
    __syncthreads();
    for (int off = 1; off < 4096; off <<= 1) {
        u32 v[4]; int c = 0;
        for (int bb = t; bb < 4096; bb += NT) { v[c++] = hist[bb] + ((bb + off < 4096) ? hist[bb + off] : 0u); }
        __syncthreads();
        c = 0;
        for (int bb = t; bb < 4096; bb += NT) hist[bb] = v[c++];
        __syncthreads();
    }
    for (int bb = t; bb < 4096; bb += NT) {
        u32 Sb  = hist[bb];
        u32 Sb1 = (bb < 4095) ? hist[bb + 1] : 0u;
        if (Sb >= PRE_NMS && Sb1 < PRE_NMS) sB1 = bb;
    }
    if (t == 0) sV = (int)hist[2048];
    __syncthreads();
    int B1 = sB1;
    int m1 = (B1 < 4095) ? (int)hist[B1 + 1] : 0;
    int V  = sV;
    __syncthreads();

    // ---- pass 2: mid 12 bits within bin B1 ----
    for (int i = t; i < 4096; i += NT) hist[i] = 0;
    __syncthreads();
    for (int i = t; i < NA; i += NT) {
        u32 key = fkey(score[i]);
        if ((int)(key >> 20) == B1) atomicAdd(&hist[(key >> 8) & 0xFFFu], 1u);
    }
    __syncthreads();
    for (int off = 1; off < 4096; off <<= 1) {
        u32 v[4]; int c = 0;
        for (int bb = t; bb < 4096; bb += NT) { v[c++] = hist[bb] + ((bb + off < 4096) ? hist[bb + off] : 0u); }
        __syncthreads();
        c = 0;
        for (int bb = t; bb < 4096; bb += NT) hist[bb] = v[c++];
        __syncthreads();
    }
    for (int bb = t; bb < 4096; bb += NT) {
        int Sb  = m1 + (int)hist[bb];
        int Sb1 = m1 + (int)((bb < 4095) ? hist[bb + 1] : 0u);
        if (Sb >= PRE_NMS && Sb1 < PRE_NMS) sB2 = bb;
    }
    __syncthreads();
    int B2 = sB2;
    int m2 = m1 + (int)((B2 < 4095) ? hist[B2 + 1] : 0u);
    u32 P24 = ((u32)B1 << 12) | (u32)B2;
    __syncthreads();

    // ---- pass 3: low 8 bits within 24-bit prefix ----
    for (int i = t; i < 256; i += NT) hist[i] = 0;
    __syncthreads();
    for (int i = t; i < NA; i += NT) {
        u32 key = fkey(score[i]);
        if ((key >> 8) == P24) atomicAdd(&hist[key & 0xFFu], 1u);
    }
    __syncthreads();
    for (int off = 1; off < 256; off <<= 1) {
        u32 v[1]; int c = 0;
        for (int bb = t; bb < 256; bb += NT) { v[c++] = hist[bb] + ((bb + off < 256) ? hist[bb + off] : 0u); }
        __syncthreads();
        c = 0;
        for (int bb = t; bb < 256; bb += NT) hist[bb] = v[c++];
        __syncthreads();
    }
    for (int bb = t; bb < 256; bb += NT) {
        int Sb  = m2 + (int)hist[bb];
        int Sb1 = m2 + (int)((bb < 255) ? hist[bb + 1] : 0u);
        if (Sb >= PRE_NMS && Sb1 < PRE_NMS) {
            sB3   = bb;
            sM3   = m2 + (int)((bb < 255) ? hist[bb + 1] : 0u);
            sNeed = PRE_NMS - sM3;
            sT32  = (P24 << 8) | (u32)bb;
        }
    }
    if (t == 0) { cHi = 0; cTie = 0; meta[0] = (V < PRE_NMS) ? V : PRE_NMS; }
    __syncthreads();
    int m3 = sM3, need = sNeed;
    u32 T32 = sT32;

    // ---- compaction: exactly 6000 entries ----
    for (int i = t; i < NA; i += NT) {
        u32 key = fkey(score[i]);
        u64 comp = ((u64)key << 32) | (u64)(0xFFFFFFFFu - (u32)i);
        if (key > T32) {
            int p = atomicAdd(&cHi, 1);
            list[p] = comp;
        } else if (key == T32) {
            int p = atomicAdd(&cTie, 1);
            if (p < need) list[m3 + p] = comp;
        }
    }
}

// =================== bitonic sort 8192 (desc) + gather cand boxes ===================
__global__ __launch_bounds__(1024) void k_sort(u64* __restrict__ list,
                                               const float* __restrict__ boxes,
                                               float* __restrict__ cand) {
    __shared__ u64 sb[8192];
    int t = threadIdx.x;
    for (int i = t; i < 8192; i += 1024) sb[i] = (i < PRE_NMS) ? list[i] : 0ull;
    __syncthreads();
    for (int k = 2; k <= 8192; k <<= 1) {
        for (int j = k >> 1; j > 0; j >>= 1) {
            for (int i = t; i < 8192; i += 1024) {
                int ixj = i ^ j;
                if (ixj > i) {
                    u64 a = sb[i], b = sb[ixj];
                    bool desc = ((i & k) == 0);
                    if (desc ? (a < b) : (a > b)) { sb[i] = b; sb[ixj] = a; }
                }
            }
            __syncthreads();
        }
    }
    for (int e = t; e < PRE_NMS; e += 1024) {
        u32 idx = 0xFFFFFFFFu - (u32)sb[e];
        float4 bx = *(const float4*)(boxes + (size_t)idx * 4);
        *(float4*)(cand + (size_t)e * 4) = bx;
    }
}

// =================== greedy NMS, early-exit at 300 survivors ===================
__global__ __launch_bounds__(256) void k_nms(const float* __restrict__ cand,
                                             const int* __restrict__ meta,
                                             float* __restrict__ rois) {
    __shared__ float kb[POST_NMS][4];
    __shared__ u64 supArr[4];
    int t = threadIdx.x;
    int lane = t & 63, wid = t >> 6;
    int keepN = meta[0];
    int kept = 0;

    for (int c0 = 0; c0 < PRE_NMS && kept < POST_NMS; c0 += 64) {
        int i = c0 + lane;
        float y1 = 0, x1 = 0, y2 = 0, x2 = 0;
        bool elig = (i < keepN);
        if (i < PRE_NMS) {
            float4 bx = *(const float4*)(cand + (size_t)i * 4);
            y1 = bx.x; x1 = bx.y; y2 = bx.z; x2 = bx.w;
        } else {
            elig = false;
        }
        float area = (y2 - y1) * (x2 - x1);

        bool supA = false;
        for (int jj = wid; jj < kept; jj += 4) {
            float ky1 = kb[jj][0], kx1 = kb[jj][1], ky2 = kb[jj][2], kx2 = kb[jj][3];
            float yy1 = fmaxf(ky1, y1), xx1 = fmaxf(kx1, x1);
            float yy2 = fminf(ky2, y2), xx2 = fminf(kx2, x2);
            float inter = fmaxf(yy2 - yy1, 0.f) * fmaxf(xx2 - xx1, 0.f);
            float karea = (ky2 - ky1) * (kx2 - kx1);
            float iou = inter / (karea + area - inter + 1e-12f);
            if (iou > 0.7f) { supA = true; break; }
        }
        supArr[wid] = __ballot(supA);
        __syncthreads();
        u64 sup = supArr[0] | supArr[1] | supArr[2] | supArr[3];
        u64 eligMask = __ballot(elig);

        for (int s = 0; s < 64; ++s) {
            if (kept >= POST_NMS) break;
            if (!((eligMask >> s) & 1ull)) continue;
            if ((sup >> s) & 1ull) continue;
            float sy1 = __shfl(y1, s), sx1 = __shfl(x1, s);
            float sy2 = __shfl(y2, s), sx2 = __shfl(x2, s);
            float sar = __shfl(area, s);
            if (wid == 0 && lane == s) {
                kb[kept][0] = y1; kb[kept][1] = x1; kb[kept][2] = y2; kb[kept][3] = x2;
                *(float4*)(rois + (size_t)kept * 4) = make_float4(y1, x1, y2, x2);
            }
            float yy1 = fmaxf(sy1, y1), xx1 = fmaxf(sx1, x1);
            float yy2 = fminf(sy2, y2), xx2 = fminf(sx2, x2);
            float inter = fmaxf(yy2 - yy1, 0.f) * fmaxf(xx2 - xx1, 0.f);
            float iou = inter / (sar + area - inter + 1e-12f);
            bool kill = (lane > s) && (iou > 0.7f);
            sup |= __ballot(kill);
            kept++;
        }
        __syncthreads();
    }
    for (int r = kept * 4 + t; r < POST_NMS * 4; r += 256) rois[r] = 0.f;
}

// =================== launcher ===================
extern "C" void kernel_launch(void* const* d_in, const int* in_sizes, int n_in,
                              void* d_out, int out_size, void* d_ws, size_t ws_size,
                              hipStream_t stream) {
    const float* feat = (const float*)d_in[0];
    const float* Wc   = (const float*)d_in[1];
    const float* bc   = (const float*)d_in[2];
    const float* Wcls = (const float*)d_in[3];
    const float* bcls = (const float*)d_in[4];
    const float* Wreg = (const float*)d_in[5];
    const float* breg = (const float*)d_in[6];
    const void* pih   = d_in[7];
    const void* piw   = d_in[8];
    float* out = (float*)d_out;
    float* ws  = (float*)d_ws;

    u64* list = (u64*)(ws + WS_LIST);
    int* meta = (int*)(ws + WS_META);

    hipLaunchKernelGGL(k_conv3, dim3(640), dim3(256), 0, stream, feat, Wc, bc, ws + WS_X);
    hipLaunchKernelGGL(k_heads, dim3(160), dim3(256), 0, stream, ws + WS_X, Wreg, breg, Wcls, bcls, out);
    hipLaunchKernelGGL(k_decode, dim3(88), dim3(256), 0, stream, out, ws, pih, piw);
    hipLaunchKernelGGL(k_select, dim3(1), dim3(1024), 0, stream, ws + WS_SCORE, list, meta);
    hipLaunchKernelGGL(k_sort, dim3(1), dim3(1024), 0, stream, list, ws + WS_BOX, ws + WS_CAND);
    hipLaunchKernelGGL(k_nms, dim3(1), dim3(256), 0, stream, ws + WS_CAND, meta, out + OUT_ROIS);
}

// Round 5
// 798.390 us; speedup vs baseline: 2.4977x; 1.2349x over previous
//
#include <hip/hip_runtime.h>
#include <cstdint>
#include <math.h>

typedef unsigned int u32;
typedef unsigned long long u64;
typedef __attribute__((ext_vector_type(8))) short short8v;   // 8 bf16 (4 VGPR)
typedef __attribute__((ext_vector_type(4))) float f32x4;     // MFMA acc

// ---------------- geometry ----------------
#define N_BATCH 8
#define C_IN    512
#define PX      2500     // 50*50
#define KDIM    4608     // 512*9
#define NA      22500
#define PRE_NMS 6000
#define POST_NMS 300

// d_out float layout (reference tuple concatenated):
// rpn_locs   [8][22500][4]  @ 0        (720000)
// rpn_scores [8][22500][2]  @ 720000   (360000)
// anchors    [22500][4]     @ 1080000  (90000)
// rois       [300][4]       @ 1170000  (1200)
#define OUT_SCORES 720000
#define OUT_ANCH   1080000
#define OUT_ROIS   1170000

// ws layout (float offsets)
#define WS_X     0            // x: 8*512*2500 floats (post-relu conv out)
#define WS_SCORE 10240000     // 22500
#define WS_BOX   10262500     // 22500*4
#define WS_LIST  10352500     // u64[6000]
#define WS_CAND  10364500     // 6000*4
#define WS_META  10388500     // ints (16)
#define WS_WP    10388608     // packed split W: 512*4608 u32 = 2,359,296  (total ws ~51 MB)

// ---------- RNE bf16 split: hi=RNE(f), lo=RNE(f - hi); pair error ~2^-18 rel ----------
__device__ inline u32 rne_hi16(float f) {
    u32 u = __float_as_uint(f);
    return (u + 0x7FFFu + ((u >> 16) & 1u)) >> 16;
}

// =================== prep: split W to bf16 hi/lo packed u32, reorder [co][r][ci] ===================
__global__ __launch_bounds__(256) void k_splitW(const float* __restrict__ Wc,
                                                u32* __restrict__ WP) {
    int o = blockIdx.x * 256 + threadIdx.x;
    if (o >= 512 * KDIM) return;
    int co  = o / KDIM;
    int rem = o - co * KDIM;
    int r   = rem >> 9;          // 0..8
    int ci  = rem & 511;
    float f = Wc[(size_t)co * KDIM + ci * 9 + r];
    u32 rh  = rne_hi16(f);
    float d = f - __uint_as_float(rh << 16);
    u32 rl  = rne_hi16(d);
    WP[o] = (rh << 16) | rl;
}

// =================== conv3x3 + bias + relu : bf16x3-split MFMA implicit GEMM ===================
// block tile 128co x 128px, K order (r, ci) in 144 tiles of 32; 4 waves, each 64x64
// grid = 4 co-tiles * 20 px-tiles * 8 n = 640
__global__ __launch_bounds__(256) void k_conv3(const float* __restrict__ in,
                                               const u32* __restrict__ WP,
                                               const float* __restrict__ bc,
                                               float* __restrict__ xout) {
    __shared__ unsigned short AsH[128][40];   // [co][k] hi
    __shared__ unsigned short AsL[128][40];   // [co][k] lo
    __shared__ unsigned short BsH[128][40];   // [px][k] hi
    __shared__ unsigned short BsL[128][40];   // [px][k] lo

    int b  = blockIdx.x;
    int cb = b & 3;
    int pt = (b >> 2) % 20;
    int n  = (b >> 2) / 20;
    int t  = threadIdx.x;
    int lane = t & 63;
    int w  = t >> 6;
    int wr = w >> 1, wc = w & 1;
    int px0 = pt * 128, co0 = cb * 128;
    const float* inN = in + (size_t)n * C_IN * PX;

    // staging roles
    int sco = t >> 1;                 // A: co 0..127
    int skb = (t & 1) << 4;           // A: k offset 0/16
    int spx = t & 127;                // B: px 0..127
    int skk = (t >> 7) << 4;          // B: k offset 0/16
    int gpx = px0 + spx;
    int sy  = gpx / 50;
    int sx  = gpx - sy * 50;
    bool pxok = (gpx < PX);
    const u32* wpA = WP + (size_t)(co0 + sco) * KDIM + skb;

    f32x4 acc[4][4];
#pragma unroll
    for (int i = 0; i < 4; ++i)
#pragma unroll
        for (int j = 0; j < 4; ++j) acc[i][j] = (f32x4)0.f;

    const int ro = lane & 15;
    const int g8 = (lane >> 4) << 3;

    for (int kstep = 0; kstep < 144; ++kstep) {
        int r   = kstep >> 4;          // 0..8  (ky*3+kx)
        int ci0 = (kstep & 15) << 5;   // 0..480
        // ---- stage A: pre-split weights, 16 packed u32 -> hi/lo ----
        {
            const u32* wp = wpA + r * 512 + ci0;
            u32 uu[16];
            *(uint4*)&uu[0]  = *(const uint4*)(wp);
            *(uint4*)&uu[4]  = *(const uint4*)(wp + 4);
            *(uint4*)&uu[8]  = *(const uint4*)(wp + 8);
            *(uint4*)&uu[12] = *(const uint4*)(wp + 12);
            short8v v0, v1, u0, u1;
#pragma unroll
            for (int e = 0; e < 8; ++e) {
                v0[e] = (short)(uu[e] >> 16);
                v1[e] = (short)(uu[8 + e] >> 16);
                u0[e] = (short)(uu[e] & 0xFFFFu);
                u1[e] = (short)(uu[8 + e] & 0xFFFFu);
            }
            *(short8v*)&AsH[sco][skb]     = v0;
            *(short8v*)&AsH[sco][skb + 8] = v1;
            *(short8v*)&AsL[sco][skb]     = u0;
            *(short8v*)&AsL[sco][skb + 8] = u1;
        }
        // ---- stage B: im2col with hoisted shift; 16 ci at stride 2500; RNE split ----
        {
            int dy = r / 3 - 1;
            int dx = r - (r / 3) * 3 - 1;
            int iy = sy + dy, ix = sx + dx;
            bool valid = pxok && ((unsigned)iy < 50u) && ((unsigned)ix < 50u);
            const float* bp = inN + (size_t)(ci0 + skk) * PX + iy * 50 + ix;
            float bv[16];
#pragma unroll
            for (int it = 0; it < 16; ++it)
                bv[it] = valid ? bp[it * PX] : 0.f;
            short8v v0, v1, u0, u1;
#pragma unroll
            for (int e = 0; e < 8; ++e) {
                u32 ha = rne_hi16(bv[e]);
                u32 hb = rne_hi16(bv[8 + e]);
                float da = bv[e]     - __uint_as_float(ha << 16);
                float db = bv[8 + e] - __uint_as_float(hb << 16);
                v0[e] = (short)ha;
                v1[e] = (short)hb;
                u0[e] = (short)rne_hi16(da);
                u1[e] = (short)rne_hi16(db);
            }
            *(short8v*)&BsH[spx][skk]     = v0;
            *(short8v*)&BsH[spx][skk + 8] = v1;
            *(short8v*)&BsL[spx][skk]     = u0;
            *(short8v*)&BsL[spx][skk + 8] = u1;
        }
        __syncthreads();

        // ---- fragments + 3-pass MFMA ----
        short8v aH[4], aL[4], bH[4], bL[4];
#pragma unroll
        for (int s = 0; s < 4; ++s) {
            aH[s] = *(const short8v*)&AsH[wr * 64 + s * 16 + ro][g8];
            aL[s] = *(const short8v*)&AsL[wr * 64 + s * 16 + ro][g8];
            bH[s] = *(const short8v*)&BsH[wc * 64 + s * 16 + ro][g8];
            bL[s] = *(const short8v*)&BsL[wc * 64 + s * 16 + ro][g8];
        }
#pragma unroll
        for (int i = 0; i < 4; ++i)
#pragma unroll
            for (int j = 0; j < 4; ++j) {
                acc[i][j] = __builtin_amdgcn_mfma_f32_16x16x32_bf16(aH[i], bH[j], acc[i][j], 0, 0, 0);
                acc[i][j] = __builtin_amdgcn_mfma_f32_16x16x32_bf16(aH[i], bL[j], acc[i][j], 0, 0, 0);
                acc[i][j] = __builtin_amdgcn_mfma_f32_16x16x32_bf16(aL[i], bH[j], acc[i][j], 0, 0, 0);
            }
        __syncthreads();
    }

    // ---- epilogue: bias + relu, fp32 store ----
    int coB  = co0 + wr * 64;
    int pxB  = px0 + wc * 64 + ro;
    int rowg = (lane >> 4) << 2;
#pragma unroll
    for (int i = 0; i < 4; ++i) {
#pragma unroll
        for (int rg = 0; rg < 4; ++rg) {
            int co = coB + i * 16 + rowg + rg;
            float bias = bc[co];
            float* dst = xout + ((size_t)n * C_IN + co) * PX;
#pragma unroll
            for (int j = 0; j < 4; ++j) {
                int px = pxB + j * 16;
                if (px < PX) dst[px] = fmaxf(acc[i][j][rg] + bias, 0.f);
            }
        }
    }
}

// =================== 1x1 heads: 54(=36 reg + 18 cls) x 512 GEMM (fp32 VALU) ===================
__global__ __launch_bounds__(256) void k_heads(const float* __restrict__ x,
                                               const float* __restrict__ Wreg,
                                               const float* __restrict__ breg,
                                               const float* __restrict__ Wcls,
                                               const float* __restrict__ bcls,
                                               float* __restrict__ out) {
    __shared__ float As[32][68];
    __shared__ float Bs[32][132];
    int b  = blockIdx.x;
    int pt = b % 20, n = b / 20;
    int t  = threadIdx.x;
    int tx = t & 15, ty = t >> 4;
    int px0 = pt * 128;
    float acc[4][8];
#pragma unroll
    for (int i = 0; i < 4; ++i)
#pragma unroll
        for (int j = 0; j < 8; ++j) acc[i][j] = 0.f;

    for (int k0 = 0; k0 < 512; k0 += 32) {
        {
            int c   = t >> 2;
            int kkb = (t & 3) << 3;
            const float* src = nullptr;
            if (c < 36)      src = Wreg + (size_t)c * 512 + k0 + kkb;
            else if (c < 54) src = Wcls + (size_t)(c - 36) * 512 + k0 + kkb;
#pragma unroll
            for (int q = 0; q < 2; ++q) {
                float4 w = src ? *(const float4*)(src + q * 4) : make_float4(0, 0, 0, 0);
                As[kkb + q * 4 + 0][c] = w.x;
                As[kkb + q * 4 + 1][c] = w.y;
                As[kkb + q * 4 + 2][c] = w.z;
                As[kkb + q * 4 + 3][c] = w.w;
            }
        }
        {
            int pxl = t & 127;
            int kk0 = (t >> 7) << 4;
            int px  = px0 + pxl;
#pragma unroll
            for (int it = 0; it < 16; ++it) {
                int kk = kk0 + it;
                float v = 0.f;
                if (px < PX) v = x[((size_t)n * 512 + k0 + kk) * PX + px];
                Bs[kk][pxl] = v;
            }
        }
        __syncthreads();
#pragma unroll 8
        for (int kk = 0; kk < 32; ++kk) {
            float a[4], bb[8];
            *(float4*)&a[0]  = *(const float4*)&As[kk][ty * 4];
            *(float4*)&bb[0] = *(const float4*)&Bs[kk][tx * 8];
            *(float4*)&bb[4] = *(const float4*)&Bs[kk][tx * 8 + 4];
#pragma unroll
            for (int i = 0; i < 4; ++i)
#pragma unroll
                for (int j = 0; j < 8; ++j)
                    acc[i][j] = fmaf(a[i], bb[j], acc[i][j]);
        }
        __syncthreads();
    }
    int pxb = px0 + tx * 8;
#pragma unroll
    for (int i = 0; i < 4; ++i) {
        int c = ty * 4 + i;
        if (c >= 54) continue;
        float bias = (c < 36) ? breg[c] : bcls[c - 36];
        for (int j = 0; j < 8; ++j) {
            int px = pxb + j;
            if (px >= PX) break;
            float v = acc[i][j] + bias;
            if (c < 36)
                out[(size_t)n * 90000 + (size_t)px * 36 + c] = v;
            else
                out[OUT_SCORES + (size_t)n * 45000 + (size_t)px * 18 + (c - 36)] = v;
        }
    }
}

// =================== anchors + decode (batch 0) ===================
__device__ inline float readDim(const void* p) {
    int v = *(const int*)p;
    if (v > 0 && v <= 100000) return (float)v;
    return *(const float*)p;
}

__global__ __launch_bounds__(256) void k_decode(float* __restrict__ dout,
                                                float* __restrict__ ws,
                                                const void* pih, const void* piw) {
    int idx = blockIdx.x * 256 + threadIdx.x;
    if (idx >= NA) return;
    float imgH = readDim(pih), imgW = readDim(piw);
    int a  = idx % 9;
    int px = idx / 9;
    int y = px / 50, x = px - y * 50;
    const float ratios[3] = {0.5f, 1.f, 2.f};
    const float scales[3] = {8.f, 16.f, 32.f};
    float r = ratios[a / 3], s = scales[a % 3];
    float hh = 16.f * s * sqrtf(r);
    float wv = 16.f * s * sqrtf(1.f / r);
    float ay1 = y * 16.f + 8.f - 0.5f * hh;
    float ax1 = x * 16.f + 8.f - 0.5f * wv;
    float ay2 = y * 16.f + 8.f + 0.5f * hh;
    float ax2 = x * 16.f + 8.f + 0.5f * wv;
    *(float4*)(dout + OUT_ANCH + (size_t)idx * 4) = make_float4(ay1, ax1, ay2, ax2);

    float4 loc = *(const float4*)(dout + (size_t)idx * 4);
    float s0 = dout[OUT_SCORES + (size_t)idx * 2];
    float s1 = dout[OUT_SCORES + (size_t)idx * 2 + 1];
    float fg = 1.f / (1.f + expf(s0 - s1));
    float ah = ay2 - ay1, aw = ax2 - ax1;
    float acy = ay1 + 0.5f * ah, acx = ax1 + 0.5f * aw;
    float cy = loc.x * ah + acy;
    float cx = loc.y * aw + acx;
    float bh = expf(loc.z) * ah;
    float bw = expf(loc.w) * aw;
    float b0 = cy - 0.5f * bh, b1 = cx - 0.5f * bw;
    float b2 = cy + 0.5f * bh, b3 = cx + 0.5f * bw;
    b0 = fminf(fmaxf(b0, 0.f), imgH);
    b1 = fminf(fmaxf(b1, 0.f), imgW);
    b2 = fminf(fmaxf(b2, 0.f), imgH);
    b3 = fminf(fmaxf(b3, 0.f), imgW);
    bool valid = ((b2 - b0) >= 16.f) && ((b3 - b1) >= 16.f);
    ws[WS_SCORE + idx] = valid ? fg : -INFINITY;
    *(float4*)(ws + WS_BOX + (size_t)idx * 4) = make_float4(b0, b1, b2, b3);
}

// =================== top-6000 threshold + compaction (single block) ===================
__device__ inline u32 fkey(float s) {
    u32 u = __float_as_uint(s);
    return (u & 0x80000000u) ? ~u : (u | 0x80000000u);
}

__global__ __launch_bounds__(1024) void k_select(const float* __restrict__ score,
                                                 u64* __restrict__ list,
                                                 int* __restrict__ meta) {
    __shared__ u32 hist[4096];
    __shared__ int sB1, sB2, sB3, sM3, sNeed, sV;
    __shared__ u32 sT32;
    __shared__ int cHi, cTie;
    int t = threadIdx.x;
    const int NT = 1024;

    for (int i = t; i < 4096; i += NT) hist[i] = 0;
    __syncthreads();
    for (int i = t; i < NA; i += NT) atomicAdd(&hist[fkey(score[i]) >> 20], 1u);
    __syncthreads();
    for (int off = 1; off < 4096; off <<= 1) {
        u32 v[4]; int c = 0;
        for (int bb = t; bb < 4096; bb += NT) { v[c++] = hist[bb] + ((bb + off < 4096) ? hist[bb + off] : 0u); }
        __syncthreads();
        c = 0;
        for (int bb = t; bb < 4096; bb += NT) hist[bb] = v[c++];
        __syncthreads();
    }
    for (int bb = t; bb < 4096; bb += NT) {
        u32 Sb  = hist[bb];
        u32 Sb1 = (bb < 4095) ? hist[bb + 1] : 0u;
        if (Sb >= PRE_NMS && Sb1 < PRE_NMS) sB1 = bb;
    }
    if (t == 0) sV = (int)hist[2048];
    __syncthreads();
    int B1 = sB1;
    int m1 = (B1 < 4095) ? (int)hist[B1 + 1] : 0;
    int V  = sV;
    __syncthreads();

    for (int i = t; i < 4096; i += NT) hist[i] = 0;
    __syncthreads();
    for (int i = t; i < NA; i += NT) {
        u32 key = fkey(score[i]);
        if ((int)(key >> 20) == B1) atomicAdd(&hist[(key >> 8) & 0xFFFu], 1u);
    }
    __syncthreads();
    for (int off = 1; off < 4096; off <<= 1) {
        u32 v[4]; int c = 0;
        for (int bb = t; bb < 4096; bb += NT) { v[c++] = hist[bb] + ((bb + off < 4096) ? hist[bb + off] : 0u); }
        __syncthreads();
        c = 0;
        for (int bb = t; bb < 4096; bb += NT) hist[bb] = v[c++];
        __syncthreads();
    }
    for (int bb = t; bb < 4096; bb += NT) {
        int Sb  = m1 + (int)hist[bb];
        int Sb1 = m1 + (int)((bb < 4095) ? hist[bb + 1] : 0u);
        if (Sb >= PRE_NMS && Sb1 < PRE_NMS) sB2 = bb;
    }
    __syncthreads();
    int B2 = sB2;
    int m2 = m1 + (int)((B2 < 4095) ? hist[B2 + 1] : 0u);
    u32 P24 = ((u32)B1 << 12) | (u32)B2;
    __syncthreads();

    for (int i = t; i < 256; i += NT) hist[i] = 0;
    __syncthreads();
    for (int i = t; i < NA; i += NT) {
        u32 key = fkey(score[i]);
        if ((key >> 8) == P24) atomicAdd(&hist[key & 0xFFu], 1u);
    }
    __syncthreads();
    for (int off = 1; off < 256; off <<= 1) {
        u32 v[1]; int c = 0;
        for (int bb = t; bb < 256; bb += NT) { v[c++] = hist[bb] + ((bb + off < 256) ? hist[bb + off] : 0u); }
        __syncthreads();
        c = 0;
        for (int bb = t; bb < 256; bb += NT) hist[bb] = v[c++];
        __syncthreads();
    }
    for (int bb = t; bb < 256; bb += NT) {
        int Sb  = m2 + (int)hist[bb];
        int Sb1 = m2 + (int)((bb < 255) ? hist[bb + 1] : 0u);
        if (Sb >= PRE_NMS && Sb1 < PRE_NMS) {
            sB3   = bb;
            sM3   = m2 + (int)((bb < 255) ? hist[bb + 1] : 0u);
            sNeed = PRE_NMS - sM3;
            sT32  = (P24 << 8) | (u32)bb;
        }
    }
    if (t == 0) { cHi = 0; cTie = 0; meta[0] = (V < PRE_NMS) ? V : PRE_NMS; }
    __syncthreads();
    int m3 = sM3, need = sNeed;
    u32 T32 = sT32;

    for (int i = t; i < NA; i += NT) {
        u32 key = fkey(score[i]);
        u64 comp = ((u64)key << 32) | (u64)(0xFFFFFFFFu - (u32)i);
        if (key > T32) {
            int p = atomicAdd(&cHi, 1);
            list[p] = comp;
        } else if (key == T32) {
            int p = atomicAdd(&cTie, 1);
            if (p < need) list[m3 + p] = comp;
        }
    }
}

// =================== bitonic sort 8192 (desc) + gather cand boxes ===================
__global__ __launch_bounds__(1024) void k_sort(u64* __restrict__ list,
                                               const float* __restrict__ boxes,
                                               float* __restrict__ cand) {
    __shared__ u64 sb[8192];
    int t = threadIdx.x;
    for (int i = t; i < 8192; i += 1024) sb[i] = (i < PRE_NMS) ? list[i] : 0ull;
    __syncthreads();
    for (int k = 2; k <= 8192; k <<= 1) {
        for (int j = k >> 1; j > 0; j >>= 1) {
            for (int i = t; i < 8192; i += 1024) {
                int ixj = i ^ j;
                if (ixj > i) {
                    u64 a = sb[i], b = sb[ixj];
                    bool desc = ((i & k) == 0);
                    if (desc ? (a < b) : (a > b)) { sb[i] = b; sb[ixj] = a; }
                }
            }
            __syncthreads();
        }
    }
    for (int e = t; e < PRE_NMS; e += 1024) {
        u32 idx = 0xFFFFFFFFu - (u32)sb[e];
        float4 bx = *(const float4*)(boxes + (size_t)idx * 4);
        *(float4*)(cand + (size_t)e * 4) = bx;
    }
}

// =================== greedy NMS, early-exit at 300 survivors ===================
__global__ __launch_bounds__(256) void k_nms(const float* __restrict__ cand,
                                             const int* __restrict__ meta,
                                             float* __restrict__ rois) {
    __shared__ float kb[POST_NMS][4];
    __shared__ u64 supArr[4];
    int t = threadIdx.x;
    int lane = t & 63, wid = t >> 6;
    int keepN = meta[0];
    int kept = 0;

    for (int c0 = 0; c0 < PRE_NMS && kept < POST_NMS; c0 += 64) {
        int i = c0 + lane;
        float y1 = 0, x1 = 0, y2 = 0, x2 = 0;
        bool elig = (i < keepN);
        if (i < PRE_NMS) {
            float4 bx = *(const float4*)(cand + (size_t)i * 4);
            y1 = bx.x; x1 = bx.y; y2 = bx.z; x2 = bx.w;
        } else {
            elig = false;
        }
        float area = (y2 - y1) * (x2 - x1);

        bool supA = false;
        for (int jj = wid; jj < kept; jj += 4) {
            float ky1 = kb[jj][0], kx1 = kb[jj][1], ky2 = kb[jj][2], kx2 = kb[jj][3];
            float yy1 = fmaxf(ky1, y1), xx1 = fmaxf(kx1, x1);
            float yy2 = fminf(ky2, y2), xx2 = fminf(kx2, x2);
            float inter = fmaxf(yy2 - yy1, 0.f) * fmaxf(xx2 - xx1, 0.f);
            float karea = (ky2 - ky1) * (kx2 - kx1);
            float iou = inter / (karea + area - inter + 1e-12f);
            if (iou > 0.7f) { supA = true; break; }
        }
        supArr[wid] = __ballot(supA);
        __syncthreads();
        u64 sup = supArr[0] | supArr[1] | supArr[2] | supArr[3];
        u64 eligMask = __ballot(elig);

        for (int s = 0; s < 64; ++s) {
            if (kept >= POST_NMS) break;
            if (!((eligMask >> s) & 1ull)) continue;
            if ((sup >> s) & 1ull) continue;
            float sy1 = __shfl(y1, s), sx1 = __shfl(x1, s);
            float sy2 = __shfl(y2, s), sx2 = __shfl(x2, s);
            float sar = __shfl(area, s);
            if (wid == 0 && lane == s) {
                kb[kept][0] = y1; kb[kept][1] = x1; kb[kept][2] = y2; kb[kept][3] = x2;
                *(float4*)(rois + (size_t)kept * 4) = make_float4(y1, x1, y2, x2);
            }
            float yy1 = fmaxf(sy1, y1), xx1 = fmaxf(sx1, x1);
            float yy2 = fminf(sy2, y2), xx2 = fminf(sx2, x2);
            float inter = fmaxf(yy2 - yy1, 0.f) * fmaxf(xx2 - xx1, 0.f);
            float iou = inter / (sar + area - inter + 1e-12f);
            bool kill = (lane > s) && (iou > 0.7f);
            sup |= __ballot(kill);
            kept++;
        }
        __syncthreads();
    }
    for (int r = kept * 4 + t; r < POST_NMS * 4; r += 256) rois[r] = 0.f;
}

// =================== launcher ===================
extern "C" void kernel_launch(void* const* d_in, const int* in_sizes, int n_in,
                              void* d_out, int out_size, void* d_ws, size_t ws_size,
                              hipStream_t stream) {
    const float* feat = (const float*)d_in[0];
    const float* Wc   = (const float*)d_in[1];
    const float* bc   = (const float*)d_in[2];
    const float* Wcls = (const float*)d_in[3];
    const float* bcls = (const float*)d_in[4];
    const float* Wreg = (const float*)d_in[5];
    const float* breg = (const float*)d_in[6];
    const void* pih   = d_in[7];
    const void* piw   = d_in[8];
    float* out = (float*)d_out;
    float* ws  = (float*)d_ws;

    u32* WP   = (u32*)(ws + WS_WP);
    u64* list = (u64*)(ws + WS_LIST);
    int* meta = (int*)(ws + WS_META);

    hipLaunchKernelGGL(k_splitW, dim3((512 * KDIM + 255) / 256), dim3(256), 0, stream, Wc, WP);
    hipLaunchKernelGGL(k_conv3, dim3(640), dim3(256), 0, stream, feat, WP, bc, ws + WS_X);
    hipLaunchKernelGGL(k_heads, dim3(160), dim3(256), 0, stream, ws + WS_X, Wreg, breg, Wcls, bcls, out);
    hipLaunchKernelGGL(k_decode, dim3(88), dim3(256), 0, stream, out, ws, pih, piw);
    hipLaunchKernelGGL(k_select, dim3(1), dim3(1024), 0, stream, ws + WS_SCORE, list, meta);
    hipLaunchKernelGGL(k_sort, dim3(1), dim3(1024), 0, stream, list, ws + WS_BOX, ws + WS_CAND);
    hipLaunchKernelGGL(k_nms, dim3(1), dim3(256), 0, stream, ws + WS_CAND, meta, out + OUT_ROIS);
}

// Round 6
// 747.629 us; speedup vs baseline: 2.6673x; 1.0679x over previous
//
#include <hip/hip_runtime.h>
#include <cstdint>
#include <math.h>

typedef unsigned int u32;
typedef unsigned long long u64;
typedef __attribute__((ext_vector_type(8))) short short8v;   // 8 bf16 (4 VGPR)
typedef __attribute__((ext_vector_type(4))) float f32x4;     // MFMA acc

// ---------------- geometry ----------------
#define N_BATCH 8
#define C_IN    512
#define PX      2500     // 50*50
#define KDIM    4608     // 512*9
#define NA      22500
#define PRE_NMS 6000
#define POST_NMS 300

// d_out float layout (reference tuple concatenated):
// rpn_locs   [8][22500][4]  @ 0        (720000)
// rpn_scores [8][22500][2]  @ 720000   (360000)
// anchors    [22500][4]     @ 1080000  (90000)
// rois       [300][4]       @ 1170000  (1200)
#define OUT_SCORES 720000
#define OUT_ANCH   1080000
#define OUT_ROIS   1170000

// ws layout (float offsets)
#define WS_X     0            // x: 8*512*2500 floats (post-relu conv out)
#define WS_SCORE 10240000     // 22500
#define WS_BOX   10262500     // 22500*4
#define WS_LIST  10352500     // u64[6000]
#define WS_CAND  10364500     // 6000*4
#define WS_META  10388500     // ints (16)
#define WS_WP    10388608     // packed split W: 512*4608 u32 = 2,359,296
#define WS_XP    12747904     // packed split X: 8*512*2500 u32 = 10,240,000 (total ~92 MB)
#define WS_END   22987904

// ---------- RNE bf16 split: hi=RNE(f), lo=RNE(f - hi); pair error ~2^-18 rel ----------
__device__ inline u32 rne_hi16(float f) {
    u32 u = __float_as_uint(f);
    return (u + 0x7FFFu + ((u >> 16) & 1u)) >> 16;
}

// =================== prep: split W, layout [co][cig][r][ci_in32] (sequential in kstep) ===================
__global__ __launch_bounds__(256) void k_splitW(const float* __restrict__ Wc,
                                                u32* __restrict__ WP) {
    int o = blockIdx.x * 256 + threadIdx.x;
    if (o >= 512 * KDIM) return;
    int ci_in = o & 31;
    int tmp   = o >> 5;           // co*144 + cig*9 + r
    int r     = tmp % 9;
    int cc    = tmp / 9;          // co*16 + cig
    int co    = cc >> 4;
    int cig   = cc & 15;
    int ci    = cig * 32 + ci_in;
    float f = Wc[(size_t)co * KDIM + ci * 9 + r];
    u32 rh  = rne_hi16(f);
    float d = f - __uint_as_float(rh << 16);
    u32 rl  = rne_hi16(d);
    WP[o] = (rh << 16) | rl;
}

// =================== prep: split input feat to packed hi|lo u32, same [n][ci][px] layout ===================
__global__ __launch_bounds__(256) void k_splitX(const float* __restrict__ in,
                                                u32* __restrict__ XP) {
    int o = blockIdx.x * 256 + threadIdx.x;
    if (o >= N_BATCH * C_IN * PX) return;
    float f = in[o];
    u32 rh  = rne_hi16(f);
    float d = f - __uint_as_float(rh << 16);
    u32 rl  = rne_hi16(d);
    XP[o] = (rh << 16) | rl;
}

// =================== conv3x3 + bias + relu : bf16x3-split MFMA implicit GEMM ===================
// block tile 128co x 128px; K order: cig outer (16), r inner (9); 4 waves 64x64 each
// grid = 640; blockIdx & 7 = batch  ->  same-batch blocks share an XCD (T1 swizzle)
__global__ __launch_bounds__(256) void k_conv3(const float* __restrict__ in,
                                               const u32* __restrict__ XP,
                                               const u32* __restrict__ WP,
                                               const float* __restrict__ bc,
                                               float* __restrict__ xout) {
    __shared__ unsigned short AsH[128][40];   // [co][k] hi
    __shared__ unsigned short AsL[128][40];   // [co][k] lo
    __shared__ unsigned short BsH[128][40];   // [px][k] hi
    __shared__ unsigned short BsL[128][40];   // [px][k] lo

    int b  = blockIdx.x;
    int n  = b & 7;               // batch -> XCD
    int q  = b >> 3;              // 0..79
    int cb = q & 3;
    int pt = q >> 2;              // 0..19
    int t  = threadIdx.x;
    int lane = t & 63;
    int w  = t >> 6;
    int wr = w >> 1, wc = w & 1;
    int px0 = pt * 128, co0 = cb * 128;
    const float* inN = in + (size_t)n * C_IN * PX;
    const u32*   XPn = XP ? (XP + (size_t)n * C_IN * PX) : nullptr;

    // staging roles
    int sco = t >> 1;                 // A: co 0..127
    int skb = (t & 1) << 4;           // A: k offset 0/16
    int spx = t & 127;                // B: px 0..127
    int skk = (t >> 7) << 4;          // B: k offset 0/16
    int gpx = px0 + spx;
    int sy  = gpx / 50;
    int sx  = gpx - sy * 50;
    bool pxok = (gpx < PX);
    const u32* wpA = WP + (size_t)(co0 + sco) * KDIM + skb;   // sequential: +32 per kstep

    f32x4 acc[4][4];
#pragma unroll
    for (int i = 0; i < 4; ++i)
#pragma unroll
        for (int j = 0; j < 4; ++j) acc[i][j] = (f32x4)0.f;

    const int ro = lane & 15;
    const int g8 = (lane >> 4) << 3;

    for (int cig = 0; cig < 16; ++cig) {
        int ci0 = cig << 5;
        for (int r = 0; r < 9; ++r) {
            int kstep = cig * 9 + r;
            // ---- stage A: sequential packed W ----
            {
                const u32* wp = wpA + kstep * 32;
                u32 uu[16];
                *(uint4*)&uu[0]  = *(const uint4*)(wp);
                *(uint4*)&uu[4]  = *(const uint4*)(wp + 4);
                *(uint4*)&uu[8]  = *(const uint4*)(wp + 8);
                *(uint4*)&uu[12] = *(const uint4*)(wp + 12);
                short8v v0, v1, u0, u1;
#pragma unroll
                for (int e = 0; e < 8; ++e) {
                    v0[e] = (short)(uu[e] >> 16);
                    v1[e] = (short)(uu[8 + e] >> 16);
                    u0[e] = (short)(uu[e] & 0xFFFFu);
                    u1[e] = (short)(uu[8 + e] & 0xFFFFu);
                }
                *(short8v*)&AsH[sco][skb]     = v0;
                *(short8v*)&AsH[sco][skb + 8] = v1;
                *(short8v*)&AsL[sco][skb]     = u0;
                *(short8v*)&AsL[sco][skb + 8] = u1;
            }
            // ---- stage B: im2col, r-inner keeps planes hot in L1/L2 ----
            {
                int ry = (r * 11) >> 5;        // r/3 for r<9
                int dy = ry - 1;
                int dx = r - ry * 3 - 1;
                int iy = sy + dy, ix = sx + dx;
                bool valid = pxok && ((unsigned)iy < 50u) && ((unsigned)ix < 50u);
                int off = iy * 50 + ix;
                short8v v0, v1, u0, u1;
                if (XPn) {
                    const u32* bp = XPn + (size_t)(ci0 + skk) * PX + off;
                    u32 uu[16];
#pragma unroll
                    for (int it = 0; it < 16; ++it)
                        uu[it] = valid ? bp[it * PX] : 0u;
#pragma unroll
                    for (int e = 0; e < 8; ++e) {
                        v0[e] = (short)(uu[e] >> 16);
                        v1[e] = (short)(uu[8 + e] >> 16);
                        u0[e] = (short)(uu[e] & 0xFFFFu);
                        u1[e] = (short)(uu[8 + e] & 0xFFFFu);
                    }
                } else {
                    const float* bp = inN + (size_t)(ci0 + skk) * PX + off;
                    float bv[16];
#pragma unroll
                    for (int it = 0; it < 16; ++it)
                        bv[it] = valid ? bp[it * PX] : 0.f;
#pragma unroll
                    for (int e = 0; e < 8; ++e) {
                        u32 ha = rne_hi16(bv[e]);
                        u32 hb = rne_hi16(bv[8 + e]);
                        float da = bv[e]     - __uint_as_float(ha << 16);
                        float db = bv[8 + e] - __uint_as_float(hb << 16);
                        v0[e] = (short)ha;
                        v1[e] = (short)hb;
                        u0[e] = (short)rne_hi16(da);
                        u1[e] = (short)rne_hi16(db);
                    }
                }
                *(short8v*)&BsH[spx][skk]     = v0;
                *(short8v*)&BsH[spx][skk + 8] = v1;
                *(short8v*)&BsL[spx][skk]     = u0;
                *(short8v*)&BsL[spx][skk + 8] = u1;
            }
            __syncthreads();

            // ---- fragments + 3-pass MFMA ----
            short8v aH[4], aL[4], bH[4], bL[4];
#pragma unroll
            for (int s = 0; s < 4; ++s) {
                aH[s] = *(const short8v*)&AsH[wr * 64 + s * 16 + ro][g8];
                aL[s] = *(const short8v*)&AsL[wr * 64 + s * 16 + ro][g8];
                bH[s] = *(const short8v*)&BsH[wc * 64 + s * 16 + ro][g8];
                bL[s] = *(const short8v*)&BsL[wc * 64 + s * 16 + ro][g8];
            }
#pragma unroll
            for (int i = 0; i < 4; ++i)
#pragma unroll
                for (int j = 0; j < 4; ++j) {
                    acc[i][j] = __builtin_amdgcn_mfma_f32_16x16x32_bf16(aH[i], bH[j], acc[i][j], 0, 0, 0);
                    acc[i][j] = __builtin_amdgcn_mfma_f32_16x16x32_bf16(aH[i], bL[j], acc[i][j], 0, 0, 0);
                    acc[i][j] = __builtin_amdgcn_mfma_f32_16x16x32_bf16(aL[i], bH[j], acc[i][j], 0, 0, 0);
                }
            __syncthreads();
        }
    }

    // ---- epilogue: bias + relu, fp32 store ----
    int coB  = co0 + wr * 64;
    int pxB  = px0 + wc * 64 + ro;
    int rowg = (lane >> 4) << 2;
#pragma unroll
    for (int i = 0; i < 4; ++i) {
#pragma unroll
        for (int rg = 0; rg < 4; ++rg) {
            int co = coB + i * 16 + rowg + rg;
            float bias = bc[co];
            float* dst = xout + ((size_t)n * C_IN + co) * PX;
#pragma unroll
            for (int j = 0; j < 4; ++j) {
                int px = pxB + j * 16;
                if (px < PX) dst[px] = fmaxf(acc[i][j][rg] + bias, 0.f);
            }
        }
    }
}

// =================== 1x1 heads: 54(=36 reg + 18 cls) x 512 GEMM (fp32 VALU) ===================
__global__ __launch_bounds__(256) void k_heads(const float* __restrict__ x,
                                               const float* __restrict__ Wreg,
                                               const float* __restrict__ breg,
                                               const float* __restrict__ Wcls,
                                               const float* __restrict__ bcls,
                                               float* __restrict__ out) {
    __shared__ float As[32][68];
    __shared__ float Bs[32][132];
    int b  = blockIdx.x;
    int pt = b % 20, n = b / 20;
    int t  = threadIdx.x;
    int tx = t & 15, ty = t >> 4;
    int px0 = pt * 128;
    float acc[4][8];
#pragma unroll
    for (int i = 0; i < 4; ++i)
#pragma unroll
        for (int j = 0; j < 8; ++j) acc[i][j] = 0.f;

    for (int k0 = 0; k0 < 512; k0 += 32) {
        {
            int c   = t >> 2;
            int kkb = (t & 3) << 3;
            const float* src = nullptr;
            if (c < 36)      src = Wreg + (size_t)c * 512 + k0 + kkb;
            else if (c < 54) src = Wcls + (size_t)(c - 36) * 512 + k0 + kkb;
#pragma unroll
            for (int q = 0; q < 2; ++q) {
                float4 w = src ? *(const float4*)(src + q * 4) : make_float4(0, 0, 0, 0);
                As[kkb + q * 4 + 0][c] = w.x;
                As[kkb + q * 4 + 1][c] = w.y;
                As[kkb + q * 4 + 2][c] = w.z;
                As[kkb + q * 4 + 3][c] = w.w;
            }
        }
        {
            int pxl = t & 127;
            int kk0 = (t >> 7) << 4;
            int px  = px0 + pxl;
#pragma unroll
            for (int it = 0; it < 16; ++it) {
                int kk = kk0 + it;
                float v = 0.f;
                if (px < PX) v = x[((size_t)n * 512 + k0 + kk) * PX + px];
                Bs[kk][pxl] = v;
            }
        }
        __syncthreads();
#pragma unroll 8
        for (int kk = 0; kk < 32; ++kk) {
            float a[4], bb[8];
            *(float4*)&a[0]  = *(const float4*)&As[kk][ty * 4];
            *(float4*)&bb[0] = *(const float4*)&Bs[kk][tx * 8];
            *(float4*)&bb[4] = *(const float4*)&Bs[kk][tx * 8 + 4];
#pragma unroll
            for (int i = 0; i < 4; ++i)
#pragma unroll
                for (int j = 0; j < 8; ++j)
                    acc[i][j] = fmaf(a[i], bb[j], acc[i][j]);
        }
        __syncthreads();
    }
    int pxb = px0 + tx * 8;
#pragma unroll
    for (int i = 0; i < 4; ++i) {
        int c = ty * 4 + i;
        if (c >= 54) continue;
        float bias = (c < 36) ? breg[c] : bcls[c - 36];
        for (int j = 0; j < 8; ++j) {
            int px = pxb + j;
            if (px >= PX) break;
            float v = acc[i][j] + bias;
            if (c < 36)
                out[(size_t)n * 90000 + (size_t)px * 36 + c] = v;
            else
                out[OUT_SCORES + (size_t)n * 45000 + (size_t)px * 18 + (c - 36)] = v;
        }
    }
}

// =================== anchors + decode (batch 0) ===================
__device__ inline float readDim(const void* p) {
    int v = *(const int*)p;
    if (v > 0 && v <= 100000) return (float)v;
    return *(const float*)p;
}

__global__ __launch_bounds__(256) void k_decode(float* __restrict__ dout,
                                                float* __restrict__ ws,
                                                const void* pih, const void* piw) {
    int idx = blockIdx.x * 256 + threadIdx.x;
    if (idx >= NA) return;
    float imgH = readDim(pih), imgW = readDim(piw);
    int a  = idx % 9;
    int px = idx / 9;
    int y = px / 50, x = px - y * 50;
    const float ratios[3] = {0.5f, 1.f, 2.f};
    const float scales[3] = {8.f, 16.f, 32.f};
    float r = ratios[a / 3], s = scales[a % 3];
    float hh = 16.f * s * sqrtf(r);
    float wv = 16.f * s * sqrtf(1.f / r);
    float ay1 = y * 16.f + 8.f - 0.5f * hh;
    float ax1 = x * 16.f + 8.f - 0.5f * wv;
    float ay2 = y * 16.f + 8.f + 0.5f * hh;
    float ax2 = x * 16.f + 8.f + 0.5f * wv;
    *(float4*)(dout + OUT_ANCH + (size_t)idx * 4) = make_float4(ay1, ax1, ay2, ax2);

    float4 loc = *(const float4*)(dout + (size_t)idx * 4);
    float s0 = dout[OUT_SCORES + (size_t)idx * 2];
    float s1 = dout[OUT_SCORES + (size_t)idx * 2 + 1];
    float fg = 1.f / (1.f + expf(s0 - s1));
    float ah = ay2 - ay1, aw = ax2 - ax1;
    float acy = ay1 + 0.5f * ah, acx = ax1 + 0.5f * aw;
    float cy = loc.x * ah + acy;
    float cx = loc.y * aw + acx;
    float bh = expf(loc.z) * ah;
    float bw = expf(loc.w) * aw;
    float b0 = cy - 0.5f * bh, b1 = cx - 0.5f * bw;
    float b2 = cy + 0.5f * bh, b3 = cx + 0.5f * bw;
    b0 = fminf(fmaxf(b0, 0.f), imgH);
    b1 = fminf(fmaxf(b1, 0.f), imgW);
    b2 = fminf(fmaxf(b2, 0.f), imgH);
    b3 = fminf(fmaxf(b3, 0.f), imgW);
    bool valid = ((b2 - b0) >= 16.f) && ((b3 - b1) >= 16.f);
    ws[WS_SCORE + idx] = valid ? fg : -INFINITY;
    *(float4*)(ws + WS_BOX + (size_t)idx * 4) = make_float4(b0, b1, b2, b3);
}

// =================== top-6000 threshold + compaction (single block) ===================
__device__ inline u32 fkey(float s) {
    u32 u = __float_as_uint(s);
    return (u & 0x80000000u) ? ~u : (u | 0x80000000u);
}

__global__ __launch_bounds__(1024) void k_select(const float* __restrict__ score,
                                                 u64* __restrict__ list,
                                                 int* __restrict__ meta) {
    __shared__ u32 hist[4096];
    __shared__ int sB1, sB2, sB3, sM3, sNeed, sV;
    __shared__ u32 sT32;
    __shared__ int cHi, cTie;
    int t = threadIdx.x;
    const int NT = 1024;

    for (int i = t; i < 4096; i += NT) hist[i] = 0;
    __syncthreads();
    for (int i = t; i < NA; i += NT) atomicAdd(&hist[fkey(score[i]) >> 20], 1u);
    __syncthreads();
    for (int off = 1; off < 4096; off <<= 1) {
        u32 v[4]; int c = 0;
        for (int bb = t; bb < 4096; bb += NT) { v[c++] = hist[bb] + ((bb + off < 4096) ? hist[bb + off] : 0u); }
        __syncthreads();
        c = 0;
        for (int bb = t; bb < 4096; bb += NT) hist[bb] = v[c++];
        __syncthreads();
    }
    for (int bb = t; bb < 4096; bb += NT) {
        u32 Sb  = hist[bb];
        u32 Sb1 = (bb < 4095) ? hist[bb + 1] : 0u;
        if (Sb >= PRE_NMS && Sb1 < PRE_NMS) sB1 = bb;
    }
    if (t == 0) sV = (int)hist[2048];
    __syncthreads();
    int B1 = sB1;
    int m1 = (B1 < 4095) ? (int)hist[B1 + 1] : 0;
    int V  = sV;
    __syncthreads();

    for (int i = t; i < 4096; i += NT) hist[i] = 0;
    __syncthreads();
    for (int i = t; i < NA; i += NT) {
        u32 key = fkey(score[i]);
        if ((int)(key >> 20) == B1) atomicAdd(&hist[(key >> 8) & 0xFFFu], 1u);
    }
    __syncthreads();
    for (int off = 1; off < 4096; off <<= 1) {
        u32 v[4]; int c = 0;
        for (int bb = t; bb < 4096; bb += NT) { v[c++] = hist[bb] + ((bb + off < 4096) ? hist[bb + off] : 0u); }
        __syncthreads();
        c = 0;
        for (int bb = t; bb < 4096; bb += NT) hist[bb] = v[c++];
        __syncthreads();
    }
    for (int bb = t; bb < 4096; bb += NT) {
        int Sb  = m1 + (int)hist[bb];
        int Sb1 = m1 + (int)((bb < 4095) ? hist[bb + 1] : 0u);
        if (Sb >= PRE_NMS && Sb1 < PRE_NMS) sB2 = bb;
    }
    __syncthreads();
    int B2 = sB2;
    int m2 = m1 + (int)((B2 < 4095) ? hist[B2 + 1] : 0u);
    u32 P24 = ((u32)B1 << 12) | (u32)B2;
    __syncthreads();

    for (int i = t; i < 256; i += NT) hist[i] = 0;
    __syncthreads();
    for (int i = t; i < NA; i += NT) {
        u32 key = fkey(score[i]);
        if ((key >> 8) == P24) atomicAdd(&hist[key & 0xFFu], 1u);
    }
    __syncthreads();
    for (int off = 1; off < 256; off <<= 1) {
        u32 v[1]; int c = 0;
        for (int bb = t; bb < 256; bb += NT) { v[c++] = hist[bb] + ((bb + off < 256) ? hist[bb + off] : 0u); }
        __syncthreads();
        c = 0;
        for (int bb = t; bb < 256; bb += NT) hist[bb] = v[c++];
        __syncthreads();
    }
    for (int bb = t; bb < 256; bb += NT) {
        int Sb  = m2 + (int)hist[bb];
        int Sb1 = m2 + (int)((bb < 255) ? hist[bb + 1] : 0u);
        if (Sb >= PRE_NMS && Sb1 < PRE_NMS) {
            sB3   = bb;
            sM3   = m2 + (int)((bb < 255) ? hist[bb + 1] : 0u);
            sNeed = PRE_NMS - sM3;
            sT32  = (P24 << 8) | (u32)bb;
        }
    }
    if (t == 0) { cHi = 0; cTie = 0; meta[0] = (V < PRE_NMS) ? V : PRE_NMS; }
    __syncthreads();
    int m3 = sM3, need = sNeed;
    u32 T32 = sT32;

    for (int i = t; i < NA; i += NT) {
        u32 key = fkey(score[i]);
        u64 comp = ((u64)key << 32) | (u64)(0xFFFFFFFFu - (u32)i);
        if (key > T32) {
            int p = atomicAdd(&cHi, 1);
            list[p] = comp;
        } else if (key == T32) {
            int p = atomicAdd(&cTie, 1);
            if (p < need) list[m3 + p] = comp;
        }
    }
}

// =================== bitonic sort 8192 (desc) + gather cand boxes ===================
__global__ __launch_bounds__(1024) void k_sort(u64* __restrict__ list,
                                               const float* __restrict__ boxes,
                                               float* __restrict__ cand) {
    __shared__ u64 sb[8192];
    int t = threadIdx.x;
    for (int i = t; i < 8192; i += 1024) sb[i] = (i < PRE_NMS) ? list[i] : 0ull;
    __syncthreads();
    for (int k = 2; k <= 8192; k <<= 1) {
        for (int j = k >> 1; j > 0; j >>= 1) {
            for (int i = t; i < 8192; i += 1024) {
                int ixj = i ^ j;
                if (ixj > i) {
                    u64 a = sb[i], b = sb[ixj];
                    bool desc = ((i & k) == 0);
                    if (desc ? (a < b) : (a > b)) { sb[i] = b; sb[ixj] = a; }
                }
            }
            __syncthreads();
        }
    }
    for (int e = t; e < PRE_NMS; e += 1024) {
        u32 idx = 0xFFFFFFFFu - (u32)sb[e];
        float4 bx = *(const float4*)(boxes + (size_t)idx * 4);
        *(float4*)(cand + (size_t)e * 4) = bx;
    }
}

// =================== greedy NMS, early-exit at 300 survivors ===================
__global__ __launch_bounds__(256) void k_nms(const float* __restrict__ cand,
                                             const int* __restrict__ meta,
                                             float* __restrict__ rois) {
    __shared__ float kb[POST_NMS][4];
    __shared__ u64 supArr[4];
    int t = threadIdx.x;
    int lane = t & 63, wid = t >> 6;
    int keepN = meta[0];
    int kept = 0;

    for (int c0 = 0; c0 < PRE_NMS && kept < POST_NMS; c0 += 64) {
        int i = c0 + lane;
        float y1 = 0, x1 = 0, y2 = 0, x2 = 0;
        bool elig = (i < keepN);
        if (i < PRE_NMS) {
            float4 bx = *(const float4*)(cand + (size_t)i * 4);
            y1 = bx.x; x1 = bx.y; y2 = bx.z; x2 = bx.w;
        } else {
            elig = false;
        }
        float area = (y2 - y1) * (x2 - x1);

        bool supA = false;
        for (int jj = wid; jj < kept; jj += 4) {
            float ky1 = kb[jj][0], kx1 = kb[jj][1], ky2 = kb[jj][2], kx2 = kb[jj][3];
            float yy1 = fmaxf(ky1, y1), xx1 = fmaxf(kx1, x1);
            float yy2 = fminf(ky2, y2), xx2 = fminf(kx2, x2);
            float inter = fmaxf(yy2 - yy1, 0.f) * fmaxf(xx2 - xx1, 0.f);
            float karea = (ky2 - ky1) * (kx2 - kx1);
            float iou = inter / (karea + area - inter + 1e-12f);
            if (iou > 0.7f) { supA = true; break; }
        }
        supArr[wid] = __ballot(supA);
        __syncthreads();
        u64 sup = supArr[0] | supArr[1] | supArr[2] | supArr[3];
        u64 eligMask = __ballot(elig);

        for (int s = 0; s < 64; ++s) {
            if (kept >= POST_NMS) break;
            if (!((eligMask >> s) & 1ull)) continue;
            if ((sup >> s) & 1ull) continue;
            float sy1 = __shfl(y1, s), sx1 = __shfl(x1, s);
            float sy2 = __shfl(y2, s), sx2 = __shfl(x2, s);
            float sar = __shfl(area, s);
            if (wid == 0 && lane == s) {
                kb[kept][0] = y1; kb[kept][1] = x1; kb[kept][2] = y2; kb[kept][3] = x2;
                *(float4*)(rois + (size_t)kept * 4) = make_float4(y1, x1, y2, x2);
            }
            float yy1 = fmaxf(sy1, y1), xx1 = fmaxf(sx1, x1);
            float yy2 = fminf(sy2, y2), xx2 = fminf(sx2, x2);
            float inter = fmaxf(yy2 - yy1, 0.f) * fmaxf(xx2 - xx1, 0.f);
            float iou = inter / (sar + area - inter + 1e-12f);
            bool kill = (lane > s) && (iou > 0.7f);
            sup |= __ballot(kill);
            kept++;
        }
        __syncthreads();
    }
    for (int r = kept * 4 + t; r < POST_NMS * 4; r += 256) rois[r] = 0.f;
}

// =================== launcher ===================
extern "C" void kernel_launch(void* const* d_in, const int* in_sizes, int n_in,
                              void* d_out, int out_size, void* d_ws, size_t ws_size,
                              hipStream_t stream) {
    const float* feat = (const float*)d_in[0];
    const float* Wc   = (const float*)d_in[1];
    const float* bc   = (const float*)d_in[2];
    const float* Wcls = (const float*)d_in[3];
    const float* bcls = (const float*)d_in[4];
    const float* Wreg = (const float*)d_in[5];
    const float* breg = (const float*)d_in[6];
    const void* pih   = d_in[7];
    const void* piw   = d_in[8];
    float* out = (float*)d_out;
    float* ws  = (float*)d_ws;

    u32* WP   = (u32*)(ws + WS_WP);
    u64* list = (u64*)(ws + WS_LIST);
    int* meta = (int*)(ws + WS_META);

    bool haveXP = (ws_size >= (size_t)WS_END * sizeof(float));
    u32* XP = haveXP ? (u32*)(ws + WS_XP) : nullptr;

    hipLaunchKernelGGL(k_splitW, dim3((512 * KDIM + 255) / 256), dim3(256), 0, stream, Wc, WP);
    if (haveXP)
        hipLaunchKernelGGL(k_splitX, dim3((N_BATCH * C_IN * PX + 255) / 256), dim3(256), 0, stream, feat, XP);
    hipLaunchKernelGGL(k_conv3, dim3(640), dim3(256), 0, stream, feat, XP, WP, bc, ws + WS_X);
    hipLaunchKernelGGL(k_heads, dim3(160), dim3(256), 0, stream, ws + WS_X, Wreg, breg, Wcls, bcls, out);
    hipLaunchKernelGGL(k_decode, dim3(88), dim3(256), 0, stream, out, ws, pih, piw);
    hipLaunchKernelGGL(k_select, dim3(1), dim3(1024), 0, stream, ws + WS_SCORE, list, meta);
    hipLaunchKernelGGL(k_sort, dim3(1), dim3(1024), 0, stream, list, ws + WS_BOX, ws + WS_CAND);
    hipLaunchKernelGGL(k_nms, dim3(1), dim3(256), 0, stream, ws + WS_CAND, meta, out + OUT_ROIS);
}

// Round 7
// 737.348 us; speedup vs baseline: 2.7045x; 1.0139x over previous
//
#include <hip/hip_runtime.h>
#include <cstdint>
#include <math.h>

typedef unsigned int u32;
typedef unsigned long long u64;
typedef __attribute__((ext_vector_type(8))) short short8v;   // 8 bf16 (4 VGPR)
typedef __attribute__((ext_vector_type(4))) float f32x4;     // MFMA acc

// ---------------- geometry ----------------
#define N_BATCH 8
#define C_IN    512
#define PX      2500     // 50*50
#define KDIM    4608     // 512*9
#define NA      22500
#define PRE_NMS 6000
#define POST_NMS 300

// d_out float layout (reference tuple concatenated):
// rpn_locs   [8][22500][4]  @ 0        (720000)
// rpn_scores [8][22500][2]  @ 720000   (360000)
// anchors    [22500][4]     @ 1080000  (90000)
// rois       [300][4]       @ 1170000  (1200)
#define OUT_SCORES 720000
#define OUT_ANCH   1080000
#define OUT_ROIS   1170000

// ws layout (float offsets)
#define WS_X     0            // x: 8*512*2500 floats (post-relu conv out)
#define WS_SCORE 10240000     // 22500
#define WS_BOX   10262500     // 22500*4
#define WS_WP    10388608     // packed split W: 512*4608 u32 = 2,359,296
#define WS_XP    12747904     // packed split X: 8*512*2500 u32 = 10,240,000 (total ~92 MB)
#define WS_END   22987904

#define NW_ELEMS (512 * KDIM)          // 2,359,296
#define NX_ELEMS (N_BATCH * C_IN * PX) // 10,240,000

// ---------- RNE bf16 split: hi=RNE(f), lo=RNE(f - hi); pair error ~2^-18 rel ----------
__device__ inline u32 rne_hi16(float f) {
    u32 u = __float_as_uint(f);
    return (u + 0x7FFFu + ((u >> 16) & 1u)) >> 16;
}
__device__ inline u32 pack_split(float f) {
    u32 rh  = rne_hi16(f);
    float d = f - __uint_as_float(rh << 16);
    u32 rl  = rne_hi16(d);
    return (rh << 16) | rl;
}

// =================== prep: split W ([co][cig][r][ci32] layout) + split X ===================
__global__ __launch_bounds__(256) void k_prep(const float* __restrict__ Wc,
                                              const float* __restrict__ in,
                                              u32* __restrict__ WP,
                                              u32* __restrict__ XP) {
    int o = blockIdx.x * 256 + threadIdx.x;
    if (o < NW_ELEMS) {
        int ci_in = o & 31;
        int tmp   = o >> 5;           // co*144 + cig*9 + r
        int r     = tmp % 9;
        int cc    = tmp / 9;          // co*16 + cig
        int co    = cc >> 4;
        int cig   = cc & 15;
        int ci    = cig * 32 + ci_in;
        WP[o] = pack_split(Wc[(size_t)co * KDIM + ci * 9 + r]);
    } else {
        int o2 = o - NW_ELEMS;
        if (o2 < NX_ELEMS && XP) XP[o2] = pack_split(in[o2]);
    }
}

// =================== conv3x3 + bias + relu : bf16x3-split MFMA implicit GEMM ===================
// block tile 128co x 128px; K order: cig outer (16), r inner (9); 4 waves 64x64 each
// grid = 640; blockIdx & 7 = batch  ->  same-batch blocks share an XCD (T1 swizzle)
__global__ __launch_bounds__(256) void k_conv3(const float* __restrict__ in,
                                               const u32* __restrict__ XP,
                                               const u32* __restrict__ WP,
                                               const float* __restrict__ bc,
                                               float* __restrict__ xout) {
    __shared__ unsigned short AsH[128][40];   // [co][k] hi
    __shared__ unsigned short AsL[128][40];   // [co][k] lo
    __shared__ unsigned short BsH[128][40];   // [px][k] hi
    __shared__ unsigned short BsL[128][40];   // [px][k] lo

    int b  = blockIdx.x;
    int n  = b & 7;               // batch -> XCD
    int q  = b >> 3;              // 0..79
    int cb = q & 3;
    int pt = q >> 2;              // 0..19
    int t  = threadIdx.x;
    int lane = t & 63;
    int w  = t >> 6;
    int wr = w >> 1, wc = w & 1;
    int px0 = pt * 128, co0 = cb * 128;
    const float* inN = in + (size_t)n * C_IN * PX;
    const u32*   XPn = XP ? (XP + (size_t)n * C_IN * PX) : nullptr;

    // staging roles
    int sco = t >> 1;                 // A: co 0..127
    int skb = (t & 1) << 4;           // A: k offset 0/16
    int spx = t & 127;                // B: px 0..127
    int skk = (t >> 7) << 4;          // B: k offset 0/16
    int gpx = px0 + spx;
    int sy  = gpx / 50;
    int sx  = gpx - sy * 50;
    bool pxok = (gpx < PX);
    const u32* wpA = WP + (size_t)(co0 + sco) * KDIM + skb;   // sequential: +32 per kstep

    f32x4 acc[4][4];
#pragma unroll
    for (int i = 0; i < 4; ++i)
#pragma unroll
        for (int j = 0; j < 4; ++j) acc[i][j] = (f32x4)0.f;

    const int ro = lane & 15;
    const int g8 = (lane >> 4) << 3;

    for (int cig = 0; cig < 16; ++cig) {
        int ci0 = cig << 5;
        for (int r = 0; r < 9; ++r) {
            int kstep = cig * 9 + r;
            // ---- stage A: sequential packed W ----
            {
                const u32* wp = wpA + kstep * 32;
                u32 uu[16];
                *(uint4*)&uu[0]  = *(const uint4*)(wp);
                *(uint4*)&uu[4]  = *(const uint4*)(wp + 4);
                *(uint4*)&uu[8]  = *(const uint4*)(wp + 8);
                *(uint4*)&uu[12] = *(const uint4*)(wp + 12);
                short8v v0, v1, u0, u1;
#pragma unroll
                for (int e = 0; e < 8; ++e) {
                    v0[e] = (short)(uu[e] >> 16);
                    v1[e] = (short)(uu[8 + e] >> 16);
                    u0[e] = (short)(uu[e] & 0xFFFFu);
                    u1[e] = (short)(uu[8 + e] & 0xFFFFu);
                }
                *(short8v*)&AsH[sco][skb]     = v0;
                *(short8v*)&AsH[sco][skb + 8] = v1;
                *(short8v*)&AsL[sco][skb]     = u0;
                *(short8v*)&AsL[sco][skb + 8] = u1;
            }
            // ---- stage B: im2col, r-inner keeps planes hot in L1/L2 ----
            {
                int ry = (r * 11) >> 5;        // r/3 for r<9
                int dy = ry - 1;
                int dx = r - ry * 3 - 1;
                int iy = sy + dy, ix = sx + dx;
                bool valid = pxok && ((unsigned)iy < 50u) && ((unsigned)ix < 50u);
                int off = iy * 50 + ix;
                short8v v0, v1, u0, u1;
                if (XPn) {
                    const u32* bp = XPn + (size_t)(ci0 + skk) * PX + off;
                    u32 uu[16];
#pragma unroll
                    for (int it = 0; it < 16; ++it)
                        uu[it] = valid ? bp[it * PX] : 0u;
#pragma unroll
                    for (int e = 0; e < 8; ++e) {
                        v0[e] = (short)(uu[e] >> 16);
                        v1[e] = (short)(uu[8 + e] >> 16);
                        u0[e] = (short)(uu[e] & 0xFFFFu);
                        u1[e] = (short)(uu[8 + e] & 0xFFFFu);
                    }
                } else {
                    const float* bp = inN + (size_t)(ci0 + skk) * PX + off;
                    float bv[16];
#pragma unroll
                    for (int it = 0; it < 16; ++it)
                        bv[it] = valid ? bp[it * PX] : 0.f;
#pragma unroll
                    for (int e = 0; e < 8; ++e) {
                        u32 pa = pack_split(bv[e]);
                        u32 pb = pack_split(bv[8 + e]);
                        v0[e] = (short)(pa >> 16);
                        v1[e] = (short)(pb >> 16);
                        u0[e] = (short)(pa & 0xFFFFu);
                        u1[e] = (short)(pb & 0xFFFFu);
                    }
                }
                *(short8v*)&BsH[spx][skk]     = v0;
                *(short8v*)&BsH[spx][skk + 8] = v1;
                *(short8v*)&BsL[spx][skk]     = u0;
                *(short8v*)&BsL[spx][skk + 8] = u1;
            }
            __syncthreads();

            // ---- fragments + 3-pass MFMA ----
            short8v aH[4], aL[4], bH[4], bL[4];
#pragma unroll
            for (int s = 0; s < 4; ++s) {
                aH[s] = *(const short8v*)&AsH[wr * 64 + s * 16 + ro][g8];
                aL[s] = *(const short8v*)&AsL[wr * 64 + s * 16 + ro][g8];
                bH[s] = *(const short8v*)&BsH[wc * 64 + s * 16 + ro][g8];
                bL[s] = *(const short8v*)&BsL[wc * 64 + s * 16 + ro][g8];
            }
#pragma unroll
            for (int i = 0; i < 4; ++i)
#pragma unroll
                for (int j = 0; j < 4; ++j) {
                    acc[i][j] = __builtin_amdgcn_mfma_f32_16x16x32_bf16(aH[i], bH[j], acc[i][j], 0, 0, 0);
                    acc[i][j] = __builtin_amdgcn_mfma_f32_16x16x32_bf16(aH[i], bL[j], acc[i][j], 0, 0, 0);
                    acc[i][j] = __builtin_amdgcn_mfma_f32_16x16x32_bf16(aL[i], bH[j], acc[i][j], 0, 0, 0);
                }
            __syncthreads();
        }
    }

    // ---- epilogue: bias + relu, fp32 store ----
    int coB  = co0 + wr * 64;
    int pxB  = px0 + wc * 64 + ro;
    int rowg = (lane >> 4) << 2;
#pragma unroll
    for (int i = 0; i < 4; ++i) {
#pragma unroll
        for (int rg = 0; rg < 4; ++rg) {
            int co = coB + i * 16 + rowg + rg;
            float bias = bc[co];
            float* dst = xout + ((size_t)n * C_IN + co) * PX;
#pragma unroll
            for (int j = 0; j < 4; ++j) {
                int px = pxB + j * 16;
                if (px < PX) dst[px] = fmaxf(acc[i][j][rg] + bias, 0.f);
            }
        }
    }
}

__device__ inline float readDim(const void* p) {
    int v = *(const int*)p;
    if (v > 0 && v <= 100000) return (float)v;
    return *(const float*)p;
}

// =================== 1x1 heads GEMM (fp32) + fused decode for batch 0 ===================
// block covers 64co (>=54) x 128px so batch-0 blocks can decode their pixels locally.
__global__ __launch_bounds__(256) void k_heads(const float* __restrict__ x,
                                               const float* __restrict__ Wreg,
                                               const float* __restrict__ breg,
                                               const float* __restrict__ Wcls,
                                               const float* __restrict__ bcls,
                                               float* __restrict__ out,
                                               float* __restrict__ wsScore,
                                               float* __restrict__ wsBox,
                                               const void* pih, const void* piw) {
    __shared__ float As[32][68];
    __shared__ float Bs[32][132];
    __shared__ float Hs[54][132];     // staged head outputs for decode (batch 0)
    int b  = blockIdx.x;
    int pt = b % 20, n = b / 20;
    int t  = threadIdx.x;
    int tx = t & 15, ty = t >> 4;
    int px0 = pt * 128;
    float acc[4][8];
#pragma unroll
    for (int i = 0; i < 4; ++i)
#pragma unroll
        for (int j = 0; j < 8; ++j) acc[i][j] = 0.f;

    for (int k0 = 0; k0 < 512; k0 += 32) {
        {
            int c   = t >> 2;
            int kkb = (t & 3) << 3;
            const float* src = nullptr;
            if (c < 36)      src = Wreg + (size_t)c * 512 + k0 + kkb;
            else if (c < 54) src = Wcls + (size_t)(c - 36) * 512 + k0 + kkb;
#pragma unroll
            for (int qq = 0; qq < 2; ++qq) {
                float4 wv = src ? *(const float4*)(src + qq * 4) : make_float4(0, 0, 0, 0);
                As[kkb + qq * 4 + 0][c] = wv.x;
                As[kkb + qq * 4 + 1][c] = wv.y;
                As[kkb + qq * 4 + 2][c] = wv.z;
                As[kkb + qq * 4 + 3][c] = wv.w;
            }
        }
        {
            int pxl = t & 127;
            int kk0 = (t >> 7) << 4;
            int px  = px0 + pxl;
#pragma unroll
            for (int it = 0; it < 16; ++it) {
                int kk = kk0 + it;
                float v = 0.f;
                if (px < PX) v = x[((size_t)n * 512 + k0 + kk) * PX + px];
                Bs[kk][pxl] = v;
            }
        }
        __syncthreads();
#pragma unroll 8
        for (int kk = 0; kk < 32; ++kk) {
            float a[4], bb[8];
            *(float4*)&a[0]  = *(const float4*)&As[kk][ty * 4];
            *(float4*)&bb[0] = *(const float4*)&Bs[kk][tx * 8];
            *(float4*)&bb[4] = *(const float4*)&Bs[kk][tx * 8 + 4];
#pragma unroll
            for (int i = 0; i < 4; ++i)
#pragma unroll
                for (int j = 0; j < 8; ++j)
                    acc[i][j] = fmaf(a[i], bb[j], acc[i][j]);
        }
        __syncthreads();
    }
    int pxb = px0 + tx * 8;
#pragma unroll
    for (int i = 0; i < 4; ++i) {
        int c = ty * 4 + i;
        if (c >= 54) continue;
        float bias = (c < 36) ? breg[c] : bcls[c - 36];
        for (int j = 0; j < 8; ++j) {
            int px = pxb + j;
            if (px >= PX) break;
            float v = acc[i][j] + bias;
            if (c < 36)
                out[(size_t)n * 90000 + (size_t)px * 36 + c] = v;
            else
                out[OUT_SCORES + (size_t)n * 45000 + (size_t)px * 18 + (c - 36)] = v;
            if (n == 0) Hs[c][tx * 8 + j] = v;
        }
    }

    // ---- fused decode + anchors for batch 0 ----
    if (n == 0) {
        __syncthreads();
        float imgH = readDim(pih), imgW = readDim(piw);
        const float ratios[3] = {0.5f, 1.f, 2.f};
        const float scales[3] = {8.f, 16.f, 32.f};
        for (int idx = t; idx < 128 * 9; idx += 256) {
            int pxl = idx / 9;
            int a   = idx - pxl * 9;
            int px  = px0 + pxl;
            if (px >= PX) continue;
            int gi = px * 9 + a;
            int y = px / 50, xq = px - y * 50;
            float r = ratios[a / 3], s = scales[a % 3];
            float hh = 16.f * s * sqrtf(r);
            float wv = 16.f * s * sqrtf(1.f / r);
            float ay1 = y * 16.f + 8.f - 0.5f * hh;
            float ax1 = xq * 16.f + 8.f - 0.5f * wv;
            float ay2 = y * 16.f + 8.f + 0.5f * hh;
            float ax2 = xq * 16.f + 8.f + 0.5f * wv;
            *(float4*)(out + OUT_ANCH + (size_t)gi * 4) = make_float4(ay1, ax1, ay2, ax2);

            float l0 = Hs[a * 4 + 0][pxl];
            float l1 = Hs[a * 4 + 1][pxl];
            float l2 = Hs[a * 4 + 2][pxl];
            float l3 = Hs[a * 4 + 3][pxl];
            float s0 = Hs[36 + 2 * a][pxl];
            float s1 = Hs[37 + 2 * a][pxl];
            float fg = 1.f / (1.f + expf(s0 - s1));
            float ah = ay2 - ay1, aw = ax2 - ax1;
            float acy = ay1 + 0.5f * ah, acx = ax1 + 0.5f * aw;
            float cy = l0 * ah + acy;
            float cx = l1 * aw + acx;
            float bh = expf(l2) * ah;
            float bw = expf(l3) * aw;
            float b0 = cy - 0.5f * bh, b1 = cx - 0.5f * bw;
            float b2 = cy + 0.5f * bh, b3 = cx + 0.5f * bw;
            b0 = fminf(fmaxf(b0, 0.f), imgH);
            b1 = fminf(fmaxf(b1, 0.f), imgW);
            b2 = fminf(fmaxf(b2, 0.f), imgH);
            b3 = fminf(fmaxf(b3, 0.f), imgW);
            bool valid = ((b2 - b0) >= 16.f) && ((b3 - b1) >= 16.f);
            wsScore[gi] = valid ? fg : -INFINITY;
            *(float4*)(wsBox + (size_t)gi * 4) = make_float4(b0, b1, b2, b3);
        }
    }
}

// =================== post: top-6000 select + bitonic sort + greedy NMS (one block) ===================
__device__ inline u32 fkey(float s) {
    u32 u = __float_as_uint(s);
    return (u & 0x80000000u) ? ~u : (u | 0x80000000u);
}

__global__ __launch_bounds__(1024) void k_post(const float* __restrict__ score,
                                               const float* __restrict__ boxes,
                                               float* __restrict__ rois) {
    __shared__ u32 hist[4096];
    __shared__ u64 sb[8192];
    __shared__ float kb[POST_NMS][4];
    __shared__ u64 supArr[16];
    __shared__ int sB1, sB2, sM3, sNeed, sV;
    __shared__ u32 sT32;
    __shared__ int cHi, cTie;
    int t = threadIdx.x;
    const int NT = 1024;

    // ---- select pass 1: top 12 bits ----
    for (int i = t; i < 4096; i += NT) hist[i] = 0;
    __syncthreads();
    for (int i = t; i < NA; i += NT) atomicAdd(&hist[fkey(score[i]) >> 20], 1u);
    __syncthreads();
    for (int off = 1; off < 4096; off <<= 1) {
        u32 v[4]; int c = 0;
        for (int bb = t; bb < 4096; bb += NT) { v[c++] = hist[bb] + ((bb + off < 4096) ? hist[bb + off] : 0u); }
        __syncthreads();
        c = 0;
        for (int bb = t; bb < 4096; bb += NT) hist[bb] = v[c++];
        __syncthreads();
    }
    for (int bb = t; bb < 4096; bb += NT) {
        u32 Sb  = hist[bb];
        u32 Sb1 = (bb < 4095) ? hist[bb + 1] : 0u;
        if (Sb >= PRE_NMS && Sb1 < PRE_NMS) sB1 = bb;
    }
    if (t == 0) sV = (int)hist[2048];
    __syncthreads();
    int B1 = sB1;
    int m1 = (B1 < 4095) ? (int)hist[B1 + 1] : 0;
    int V  = sV;
    __syncthreads();

    // ---- select pass 2: mid 12 bits ----
    for (int i = t; i < 4096; i += NT) hist[i] = 0;
    __syncthreads();
    for (int i = t; i < NA; i += NT) {
        u32 key = fkey(score[i]);
        if ((int)(key >> 20) == B1) atomicAdd(&hist[(key >> 8) & 0xFFFu], 1u);
    }
    __syncthreads();
    for (int off = 1; off < 4096; off <<= 1) {
        u32 v[4]; int c = 0;
        for (int bb = t; bb < 4096; bb += NT) { v[c++] = hist[bb] + ((bb + off < 4096) ? hist[bb + off] : 0u); }
        __syncthreads();
        c = 0;
        for (int bb = t; bb < 4096; bb += NT) hist[bb] = v[c++];
        __syncthreads();
    }
    for (int bb = t; bb < 4096; bb += NT) {
        int Sb  = m1 + (int)hist[bb];
        int Sb1 = m1 + (int)((bb < 4095) ? hist[bb + 1] : 0u);
        if (Sb >= PRE_NMS && Sb1 < PRE_NMS) sB2 = bb;
    }
    __syncthreads();
    int B2 = sB2;
    int m2 = m1 + (int)((B2 < 4095) ? hist[B2 + 1] : 0u);
    u32 P24 = ((u32)B1 << 12) | (u32)B2;
    __syncthreads();

    // ---- select pass 3: low 8 bits ----
    for (int i = t; i < 256; i += NT) hist[i] = 0;
    __syncthreads();
    for (int i = t; i < NA; i += NT) {
        u32 key = fkey(score[i]);
        if ((key >> 8) == P24) atomicAdd(&hist[key & 0xFFu], 1u);
    }
    __syncthreads();
    for (int off = 1; off < 256; off <<= 1) {
        u32 v[1]; int c = 0;
        for (int bb = t; bb < 256; bb += NT) { v[c++] = hist[bb] + ((bb + off < 256) ? hist[bb + off] : 0u); }
        __syncthreads();
        c = 0;
        for (int bb = t; bb < 256; bb += NT) hist[bb] = v[c++];
        __syncthreads();
    }
    for (int bb = t; bb < 256; bb += NT) {
        int Sb  = m2 + (int)hist[bb];
        int Sb1 = m2 + (int)((bb < 255) ? hist[bb + 1] : 0u);
        if (Sb >= PRE_NMS && Sb1 < PRE_NMS) {
            sM3   = m2 + (int)((bb < 255) ? hist[bb + 1] : 0u);
            sNeed = PRE_NMS - sM3;
            sT32  = (P24 << 8) | (u32)bb;
        }
    }
    if (t == 0) { cHi = 0; cTie = 0; }
    __syncthreads();
    int m3 = sM3, need = sNeed;
    u32 T32 = sT32;

    // ---- compaction straight into LDS sb[0..5999]; pad 6000..8191 with 0 ----
    for (int i = t; i < NA; i += NT) {
        u32 key = fkey(score[i]);
        u64 comp = ((u64)key << 32) | (u64)(0xFFFFFFFFu - (u32)i);
        if (key > T32) {
            int p = atomicAdd(&cHi, 1);
            sb[p] = comp;
        } else if (key == T32) {
            int p = atomicAdd(&cTie, 1);
            if (p < need) sb[m3 + p] = comp;
        }
    }
    for (int i = PRE_NMS + t; i < 8192; i += NT) sb[i] = 0ull;
    __syncthreads();

    // ---- bitonic sort 8192 desc ----
    for (int k = 2; k <= 8192; k <<= 1) {
        for (int j = k >> 1; j > 0; j >>= 1) {
            for (int i = t; i < 8192; i += NT) {
                int ixj = i ^ j;
                if (ixj > i) {
                    u64 a = sb[i], bbv = sb[ixj];
                    bool desc = ((i & k) == 0);
                    if (desc ? (a < bbv) : (a > bbv)) { sb[i] = bbv; sb[ixj] = a; }
                }
            }
            __syncthreads();
        }
    }

    // ---- greedy NMS, early exit at 300 ----
    int lane = t & 63, wid = t >> 6;
    int keepN = (V < PRE_NMS) ? V : PRE_NMS;
    int kept = 0;

    for (int c0 = 0; c0 < PRE_NMS && kept < POST_NMS; c0 += 64) {
        int i = c0 + lane;
        float y1 = 0, x1 = 0, y2 = 0, x2 = 0;
        bool elig = (i < keepN);
        {
            u32 bidx = 0xFFFFFFFFu - (u32)sb[i];
            float4 bx = *(const float4*)(boxes + (size_t)bidx * 4);
            y1 = bx.x; x1 = bx.y; y2 = bx.z; x2 = bx.w;
        }
        float area = (y2 - y1) * (x2 - x1);

        bool supA = false;
        for (int jj = wid; jj < kept; jj += 16) {
            float ky1 = kb[jj][0], kx1 = kb[jj][1], ky2 = kb[jj][2], kx2 = kb[jj][3];
            float yy1 = fmaxf(ky1, y1), xx1 = fmaxf(kx1, x1);
            float yy2 = fminf(ky2, y2), xx2 = fminf(kx2, x2);
            float inter = fmaxf(yy2 - yy1, 0.f) * fmaxf(xx2 - xx1, 0.f);
            float karea = (ky2 - ky1) * (kx2 - kx1);
            float iou = inter / (karea + area - inter + 1e-12f);
            if (iou > 0.7f) { supA = true; break; }
        }
        supArr[wid] = __ballot(supA);
        __syncthreads();
        u64 sup = 0ull;
#pragma unroll
        for (int ww = 0; ww < 16; ++ww) sup |= supArr[ww];
        u64 eligMask = __ballot(elig);

        for (int s = 0; s < 64; ++s) {
            if (kept >= POST_NMS) break;
            if (!((eligMask >> s) & 1ull)) continue;
            if ((sup >> s) & 1ull) continue;
            float sy1 = __shfl(y1, s), sx1 = __shfl(x1, s);
            float sy2 = __shfl(y2, s), sx2 = __shfl(x2, s);
            float sar = __shfl(area, s);
            if (wid == 0 && lane == s) {
                kb[kept][0] = y1; kb[kept][1] = x1; kb[kept][2] = y2; kb[kept][3] = x2;
                *(float4*)(rois + (size_t)kept * 4) = make_float4(y1, x1, y2, x2);
            }
            float yy1 = fmaxf(sy1, y1), xx1 = fmaxf(sx1, x1);
            float yy2 = fminf(sy2, y2), xx2 = fminf(sx2, x2);
            float inter = fmaxf(yy2 - yy1, 0.f) * fmaxf(xx2 - xx1, 0.f);
            float iou = inter / (sar + area - inter + 1e-12f);
            bool kill = (lane > s) && (iou > 0.7f);
            sup |= __ballot(kill);
            kept++;
        }
        __syncthreads();
    }
    for (int r = kept * 4 + t; r < POST_NMS * 4; r += NT) rois[r] = 0.f;
}

// =================== launcher ===================
extern "C" void kernel_launch(void* const* d_in, const int* in_sizes, int n_in,
                              void* d_out, int out_size, void* d_ws, size_t ws_size,
                              hipStream_t stream) {
    const float* feat = (const float*)d_in[0];
    const float* Wc   = (const float*)d_in[1];
    const float* bc   = (const float*)d_in[2];
    const float* Wcls = (const float*)d_in[3];
    const float* bcls = (const float*)d_in[4];
    const float* Wreg = (const float*)d_in[5];
    const float* breg = (const float*)d_in[6];
    const void* pih   = d_in[7];
    const void* piw   = d_in[8];
    float* out = (float*)d_out;
    float* ws  = (float*)d_ws;

    u32* WP = (u32*)(ws + WS_WP);
    bool haveXP = (ws_size >= (size_t)WS_END * sizeof(float));
    u32* XP = haveXP ? (u32*)(ws + WS_XP) : nullptr;

    int prepItems = NW_ELEMS + (haveXP ? NX_ELEMS : 0);
    hipLaunchKernelGGL(k_prep, dim3((prepItems + 255) / 256), dim3(256), 0, stream, Wc, feat, WP, XP);
    hipLaunchKernelGGL(k_conv3, dim3(640), dim3(256), 0, stream, feat, XP, WP, bc, ws + WS_X);
    hipLaunchKernelGGL(k_heads, dim3(160), dim3(256), 0, stream, ws + WS_X, Wreg, breg, Wcls, bcls,
                       out, ws + WS_SCORE, ws + WS_BOX, pih, piw);
    hipLaunchKernelGGL(k_post, dim3(1), dim3(1024), 0, stream, ws + WS_SCORE, ws + WS_BOX, out + OUT_ROIS);
}

// Round 8
// 635.131 us; speedup vs baseline: 3.1397x; 1.1609x over previous
//
#include <hip/hip_runtime.h>
#include <cstdint>
#include <math.h>

typedef unsigned int u32;
typedef unsigned long long u64;
typedef __attribute__((ext_vector_type(8))) short short8v;   // 8 bf16 (4 VGPR)
typedef __attribute__((ext_vector_type(4))) float f32x4;     // MFMA acc

// ---------------- geometry ----------------
#define N_BATCH 8
#define C_IN    512
#define PX      2500     // 50*50
#define KDIM    4608     // 512*9
#define NA      22500
#define PRE_NMS 6000
#define POST_NMS 300

// d_out float layout (reference tuple concatenated):
// rpn_locs   [8][22500][4]  @ 0        (720000)
// rpn_scores [8][22500][2]  @ 720000   (360000)
// anchors    [22500][4]     @ 1080000  (90000)
// rois       [300][4]       @ 1170000  (1200)
#define OUT_SCORES 720000
#define OUT_ANCH   1080000
#define OUT_ROIS   1170000

// ws layout (float offsets)
#define WS_X     0            // x: 8*512*2500 floats (post-relu conv out)
#define WS_SCORE 10240000     // 22500
#define WS_BOX   10262500     // 22500*4
#define WS_LIST  10352500     // u64[8192] = 16384 floats (8B aligned)
#define WS_META  10388500     // ints (16)
#define WS_WP    10388608     // packed split W: 512*4608 u32 = 2,359,296
#define WS_XP    12747904     // packed split X: 8*512*2500 u32 = 10,240,000 (total ~92 MB)
#define WS_END   22987904

#define NW_ELEMS (512 * KDIM)          // 2,359,296
#define NX_ELEMS (N_BATCH * C_IN * PX) // 10,240,000

// ---------- RNE bf16 split: hi=RNE(f), lo=RNE(f - hi); pair error ~2^-18 rel ----------
__device__ inline u32 rne_hi16(float f) {
    u32 u = __float_as_uint(f);
    return (u + 0x7FFFu + ((u >> 16) & 1u)) >> 16;
}
__device__ inline u32 pack_split(float f) {
    u32 rh  = rne_hi16(f);
    float d = f - __uint_as_float(rh << 16);
    u32 rl  = rne_hi16(d);
    return (rh << 16) | rl;
}

// =================== prep: split W ([co][cig][r][ci32] layout) + split X ===================
__global__ __launch_bounds__(256) void k_prep(const float* __restrict__ Wc,
                                              const float* __restrict__ in,
                                              u32* __restrict__ WP,
                                              u32* __restrict__ XP) {
    int o = blockIdx.x * 256 + threadIdx.x;
    if (o < NW_ELEMS) {
        int ci_in = o & 31;
        int tmp   = o >> 5;           // co*144 + cig*9 + r
        int r     = tmp % 9;
        int cc    = tmp / 9;          // co*16 + cig
        int co    = cc >> 4;
        int cig   = cc & 15;
        int ci    = cig * 32 + ci_in;
        WP[o] = pack_split(Wc[(size_t)co * KDIM + ci * 9 + r]);
    } else {
        int o2 = o - NW_ELEMS;
        if (o2 < NX_ELEMS && XP) XP[o2] = pack_split(in[o2]);
    }
}

// =================== conv3x3 + bias + relu : bf16x3-split MFMA implicit GEMM ===================
// block tile 128co x 128px; K order: cig outer (16), r inner (9); 4 waves 64x64 each
// grid = 640; blockIdx & 7 = batch  ->  same-batch blocks share an XCD (T1 swizzle)
__global__ __launch_bounds__(256) void k_conv3(const float* __restrict__ in,
                                               const u32* __restrict__ XP,
                                               const u32* __restrict__ WP,
                                               const float* __restrict__ bc,
                                               float* __restrict__ xout) {
    __shared__ unsigned short AsH[128][40];   // [co][k] hi
    __shared__ unsigned short AsL[128][40];   // [co][k] lo
    __shared__ unsigned short BsH[128][40];   // [px][k] hi
    __shared__ unsigned short BsL[128][40];   // [px][k] lo

    int b  = blockIdx.x;
    int n  = b & 7;               // batch -> XCD
    int q  = b >> 3;              // 0..79
    int cb = q & 3;
    int pt = q >> 2;              // 0..19
    int t  = threadIdx.x;
    int lane = t & 63;
    int w  = t >> 6;
    int wr = w >> 1, wc = w & 1;
    int px0 = pt * 128, co0 = cb * 128;
    const float* inN = in + (size_t)n * C_IN * PX;
    const u32*   XPn = XP ? (XP + (size_t)n * C_IN * PX) : nullptr;

    // staging roles
    int sco = t >> 1;                 // A: co 0..127
    int skb = (t & 1) << 4;           // A: k offset 0/16
    int spx = t & 127;                // B: px 0..127
    int skk = (t >> 7) << 4;          // B: k offset 0/16
    int gpx = px0 + spx;
    int sy  = gpx / 50;
    int sx  = gpx - sy * 50;
    bool pxok = (gpx < PX);
    const u32* wpA = WP + (size_t)(co0 + sco) * KDIM + skb;   // sequential: +32 per kstep

    f32x4 acc[4][4];
#pragma unroll
    for (int i = 0; i < 4; ++i)
#pragma unroll
        for (int j = 0; j < 4; ++j) acc[i][j] = (f32x4)0.f;

    const int ro = lane & 15;
    const int g8 = (lane >> 4) << 3;

    for (int cig = 0; cig < 16; ++cig) {
        int ci0 = cig << 5;
        for (int r = 0; r < 9; ++r) {
            int kstep = cig * 9 + r;
            // ---- stage A: sequential packed W ----
            {
                const u32* wp = wpA + kstep * 32;
                u32 uu[16];
                *(uint4*)&uu[0]  = *(const uint4*)(wp);
                *(uint4*)&uu[4]  = *(const uint4*)(wp + 4);
                *(uint4*)&uu[8]  = *(const uint4*)(wp + 8);
                *(uint4*)&uu[12] = *(const uint4*)(wp + 12);
                short8v v0, v1, u0, u1;
#pragma unroll
                for (int e = 0; e < 8; ++e) {
                    v0[e] = (short)(uu[e] >> 16);
                    v1[e] = (short)(uu[8 + e] >> 16);
                    u0[e] = (short)(uu[e] & 0xFFFFu);
                    u1[e] = (short)(uu[8 + e] & 0xFFFFu);
                }
                *(short8v*)&AsH[sco][skb]     = v0;
                *(short8v*)&AsH[sco][skb + 8] = v1;
                *(short8v*)&AsL[sco][skb]     = u0;
                *(short8v*)&AsL[sco][skb + 8] = u1;
            }
            // ---- stage B: im2col, r-inner keeps planes hot in L1/L2 ----
            {
                int ry = (r * 11) >> 5;        // r/3 for r<9
                int dy = ry - 1;
                int dx = r - ry * 3 - 1;
                int iy = sy + dy, ix = sx + dx;
                bool valid = pxok && ((unsigned)iy < 50u) && ((unsigned)ix < 50u);
                int off = iy * 50 + ix;
                short8v v0, v1, u0, u1;
                if (XPn) {
                    const u32* bp = XPn + (size_t)(ci0 + skk) * PX + off;
                    u32 uu[16];
#pragma unroll
                    for (int it = 0; it < 16; ++it)
                        uu[it] = valid ? bp[it * PX] : 0u;
#pragma unroll
                    for (int e = 0; e < 8; ++e) {
                        v0[e] = (short)(uu[e] >> 16);
                        v1[e] = (short)(uu[8 + e] >> 16);
                        u0[e] = (short)(uu[e] & 0xFFFFu);
                        u1[e] = (short)(uu[8 + e] & 0xFFFFu);
                    }
                } else {
                    const float* bp = inN + (size_t)(ci0 + skk) * PX + off;
                    float bv[16];
#pragma unroll
                    for (int it = 0; it < 16; ++it)
                        bv[it] = valid ? bp[it * PX] : 0.f;
#pragma unroll
                    for (int e = 0; e < 8; ++e) {
                        u32 pa = pack_split(bv[e]);
                        u32 pb = pack_split(bv[8 + e]);
                        v0[e] = (short)(pa >> 16);
                        v1[e] = (short)(pb >> 16);
                        u0[e] = (short)(pa & 0xFFFFu);
                        u1[e] = (short)(pb & 0xFFFFu);
                    }
                }
                *(short8v*)&BsH[spx][skk]     = v0;
                *(short8v*)&BsH[spx][skk + 8] = v1;
                *(short8v*)&BsL[spx][skk]     = u0;
                *(short8v*)&BsL[spx][skk + 8] = u1;
            }
            __syncthreads();

            // ---- fragments + 3-pass MFMA ----
            short8v aH[4], aL[4], bH[4], bL[4];
#pragma unroll
            for (int s = 0; s < 4; ++s) {
                aH[s] = *(const short8v*)&AsH[wr * 64 + s * 16 + ro][g8];
                aL[s] = *(const short8v*)&AsL[wr * 64 + s * 16 + ro][g8];
                bH[s] = *(const short8v*)&BsH[wc * 64 + s * 16 + ro][g8];
                bL[s] = *(const short8v*)&BsL[wc * 64 + s * 16 + ro][g8];
            }
#pragma unroll
            for (int i = 0; i < 4; ++i)
#pragma unroll
                for (int j = 0; j < 4; ++j) {
                    acc[i][j] = __builtin_amdgcn_mfma_f32_16x16x32_bf16(aH[i], bH[j], acc[i][j], 0, 0, 0);
                    acc[i][j] = __builtin_amdgcn_mfma_f32_16x16x32_bf16(aH[i], bL[j], acc[i][j], 0, 0, 0);
                    acc[i][j] = __builtin_amdgcn_mfma_f32_16x16x32_bf16(aL[i], bH[j], acc[i][j], 0, 0, 0);
                }
            __syncthreads();
        }
    }

    // ---- epilogue: bias + relu, fp32 store ----
    int coB  = co0 + wr * 64;
    int pxB  = px0 + wc * 64 + ro;
    int rowg = (lane >> 4) << 2;
#pragma unroll
    for (int i = 0; i < 4; ++i) {
#pragma unroll
        for (int rg = 0; rg < 4; ++rg) {
            int co = coB + i * 16 + rowg + rg;
            float bias = bc[co];
            float* dst = xout + ((size_t)n * C_IN + co) * PX;
#pragma unroll
            for (int j = 0; j < 4; ++j) {
                int px = pxB + j * 16;
                if (px < PX) dst[px] = fmaxf(acc[i][j][rg] + bias, 0.f);
            }
        }
    }
}

__device__ inline float readDim(const void* p) {
    int v = *(const int*)p;
    if (v > 0 && v <= 100000) return (float)v;
    return *(const float*)p;
}

// =================== 1x1 heads GEMM (fp32) + fused decode for batch 0 ===================
__global__ __launch_bounds__(256) void k_heads(const float* __restrict__ x,
                                               const float* __restrict__ Wreg,
                                               const float* __restrict__ breg,
                                               const float* __restrict__ Wcls,
                                               const float* __restrict__ bcls,
                                               float* __restrict__ out,
                                               float* __restrict__ wsScore,
                                               float* __restrict__ wsBox,
                                               const void* pih, const void* piw) {
    __shared__ float As[32][68];
    __shared__ float Bs[32][132];
    __shared__ float Hs[54][132];     // staged head outputs for decode (batch 0)
    int b  = blockIdx.x;
    int pt = b % 20, n = b / 20;
    int t  = threadIdx.x;
    int tx = t & 15, ty = t >> 4;
    int px0 = pt * 128;
    float acc[4][8];
#pragma unroll
    for (int i = 0; i < 4; ++i)
#pragma unroll
        for (int j = 0; j < 8; ++j) acc[i][j] = 0.f;

    for (int k0 = 0; k0 < 512; k0 += 32) {
        {
            int c   = t >> 2;
            int kkb = (t & 3) << 3;
            const float* src = nullptr;
            if (c < 36)      src = Wreg + (size_t)c * 512 + k0 + kkb;
            else if (c < 54) src = Wcls + (size_t)(c - 36) * 512 + k0 + kkb;
#pragma unroll
            for (int qq = 0; qq < 2; ++qq) {
                float4 wv = src ? *(const float4*)(src + qq * 4) : make_float4(0, 0, 0, 0);
                As[kkb + qq * 4 + 0][c] = wv.x;
                As[kkb + qq * 4 + 1][c] = wv.y;
                As[kkb + qq * 4 + 2][c] = wv.z;
                As[kkb + qq * 4 + 3][c] = wv.w;
            }
        }
        {
            int pxl = t & 127;
            int kk0 = (t >> 7) << 4;
            int px  = px0 + pxl;
#pragma unroll
            for (int it = 0; it < 16; ++it) {
                int kk = kk0 + it;
                float v = 0.f;
                if (px < PX) v = x[((size_t)n * 512 + k0 + kk) * PX + px];
                Bs[kk][pxl] = v;
            }
        }
        __syncthreads();
#pragma unroll 8
        for (int kk = 0; kk < 32; ++kk) {
            float a[4], bb[8];
            *(float4*)&a[0]  = *(const float4*)&As[kk][ty * 4];
            *(float4*)&bb[0] = *(const float4*)&Bs[kk][tx * 8];
            *(float4*)&bb[4] = *(const float4*)&Bs[kk][tx * 8 + 4];
#pragma unroll
            for (int i = 0; i < 4; ++i)
#pragma unroll
                for (int j = 0; j < 8; ++j)
                    acc[i][j] = fmaf(a[i], bb[j], acc[i][j]);
        }
        __syncthreads();
    }
    int pxb = px0 + tx * 8;
#pragma unroll
    for (int i = 0; i < 4; ++i) {
        int c = ty * 4 + i;
        if (c >= 54) continue;
        float bias = (c < 36) ? breg[c] : bcls[c - 36];
        for (int j = 0; j < 8; ++j) {
            int px = pxb + j;
            if (px >= PX) break;
            float v = acc[i][j] + bias;
            if (c < 36)
                out[(size_t)n * 90000 + (size_t)px * 36 + c] = v;
            else
                out[OUT_SCORES + (size_t)n * 45000 + (size_t)px * 18 + (c - 36)] = v;
            if (n == 0) Hs[c][tx * 8 + j] = v;
        }
    }

    // ---- fused decode + anchors for batch 0 ----
    if (n == 0) {
        __syncthreads();
        float imgH = readDim(pih), imgW = readDim(piw);
        const float ratios[3] = {0.5f, 1.f, 2.f};
        const float scales[3] = {8.f, 16.f, 32.f};
        for (int idx = t; idx < 128 * 9; idx += 256) {
            int pxl = idx / 9;
            int a   = idx - pxl * 9;
            int px  = px0 + pxl;
            if (px >= PX) continue;
            int gi = px * 9 + a;
            int y = px / 50, xq = px - y * 50;
            float r = ratios[a / 3], s = scales[a % 3];
            float hh = 16.f * s * sqrtf(r);
            float wv = 16.f * s * sqrtf(1.f / r);
            float ay1 = y * 16.f + 8.f - 0.5f * hh;
            float ax1 = xq * 16.f + 8.f - 0.5f * wv;
            float ay2 = y * 16.f + 8.f + 0.5f * hh;
            float ax2 = xq * 16.f + 8.f + 0.5f * wv;
            *(float4*)(out + OUT_ANCH + (size_t)gi * 4) = make_float4(ay1, ax1, ay2, ax2);

            float l0 = Hs[a * 4 + 0][pxl];
            float l1 = Hs[a * 4 + 1][pxl];
            float l2 = Hs[a * 4 + 2][pxl];
            float l3 = Hs[a * 4 + 3][pxl];
            float s0 = Hs[36 + 2 * a][pxl];
            float s1 = Hs[37 + 2 * a][pxl];
            float fg = 1.f / (1.f + expf(s0 - s1));
            float ah = ay2 - ay1, aw = ax2 - ax1;
            float acy = ay1 + 0.5f * ah, acx = ax1 + 0.5f * aw;
            float cy = l0 * ah + acy;
            float cx = l1 * aw + acx;
            float bh = expf(l2) * ah;
            float bw = expf(l3) * aw;
            float b0 = cy - 0.5f * bh, b1 = cx - 0.5f * bw;
            float b2 = cy + 0.5f * bh, b3 = cx + 0.5f * bw;
            b0 = fminf(fmaxf(b0, 0.f), imgH);
            b1 = fminf(fmaxf(b1, 0.f), imgW);
            b2 = fminf(fmaxf(b2, 0.f), imgH);
            b3 = fminf(fmaxf(b3, 0.f), imgW);
            bool valid = ((b2 - b0) >= 16.f) && ((b3 - b1) >= 16.f);
            wsScore[gi] = valid ? fg : -INFINITY;
            *(float4*)(wsBox + (size_t)gi * 4) = make_float4(b0, b1, b2, b3);
        }
    }
}

// =================== select: top-6000 threshold + compaction -> global list ===================
__device__ inline u32 fkey(float s) {
    u32 u = __float_as_uint(s);
    return (u & 0x80000000u) ? ~u : (u | 0x80000000u);
}

__global__ __launch_bounds__(1024) void k_select(const float* __restrict__ score,
                                                 u64* __restrict__ list,
                                                 int* __restrict__ meta) {
    __shared__ u32 hist[4096];
    __shared__ int sB1, sB2, sM3, sNeed, sV;
    __shared__ u32 sT32;
    __shared__ int cHi, cTie;
    int t = threadIdx.x;
    const int NT = 1024;

    // ---- pass 1: top 12 bits ----
    for (int i = t; i < 4096; i += NT) hist[i] = 0;
    __syncthreads();
    for (int i = t; i < NA; i += NT) atomicAdd(&hist[fkey(score[i]) >> 20], 1u);
    __syncthreads();
    for (int off = 1; off < 4096; off <<= 1) {
        u32 v[4]; int c = 0;
        for (int bb = t; bb < 4096; bb += NT) { v[c++] = hist[bb] + ((bb + off < 4096) ? hist[bb + off] : 0u); }
        __syncthreads();
        c = 0;
        for (int bb = t; bb < 4096; bb += NT) hist[bb] = v[c++];
        __syncthreads();
    }
    for (int bb = t; bb < 4096; bb += NT) {
        u32 Sb  = hist[bb];
        u32 Sb1 = (bb < 4095) ? hist[bb + 1] : 0u;
        if (Sb >= PRE_NMS && Sb1 < PRE_NMS) sB1 = bb;
    }
    if (t == 0) sV = (int)hist[2048];
    __syncthreads();
    int B1 = sB1;
    int m1 = (B1 < 4095) ? (int)hist[B1 + 1] : 0;
    int V  = sV;
    __syncthreads();

    // ---- pass 2: mid 12 bits ----
    for (int i = t; i < 4096; i += NT) hist[i] = 0;
    __syncthreads();
    for (int i = t; i < NA; i += NT) {
        u32 key = fkey(score[i]);
        if ((int)(key >> 20) == B1) atomicAdd(&hist[(key >> 8) & 0xFFFu], 1u);
    }
    __syncthreads();
    for (int off = 1; off < 4096; off <<= 1) {
        u32 v[4]; int c = 0;
        for (int bb = t; bb < 4096; bb += NT) { v[c++] = hist[bb] + ((bb + off < 4096) ? hist[bb + off] : 0u); }
        __syncthreads();
        c = 0;
        for (int bb = t; bb < 4096; bb += NT) hist[bb] = v[c++];
        __syncthreads();
    }
    for (int bb = t; bb < 4096; bb += NT) {
        int Sb  = m1 + (int)hist[bb];
        int Sb1 = m1 + (int)((bb < 4095) ? hist[bb + 1] : 0u);
        if (Sb >= PRE_NMS && Sb1 < PRE_NMS) sB2 = bb;
    }
    __syncthreads();
    int B2 = sB2;
    int m2 = m1 + (int)((B2 < 4095) ? hist[B2 + 1] : 0u);
    u32 P24 = ((u32)B1 << 12) | (u32)B2;
    __syncthreads();

    // ---- pass 3: low 8 bits ----
    for (int i = t; i < 256; i += NT) hist[i] = 0;
    __syncthreads();
    for (int i = t; i < NA; i += NT) {
        u32 key = fkey(score[i]);
        if ((key >> 8) == P24) atomicAdd(&hist[key & 0xFFu], 1u);
    }
    __syncthreads();
    for (int off = 1; off < 256; off <<= 1) {
        u32 v[1]; int c = 0;
        for (int bb = t; bb < 256; bb += NT) { v[c++] = hist[bb] + ((bb + off < 256) ? hist[bb + off] : 0u); }
        __syncthreads();
        c = 0;
        for (int bb = t; bb < 256; bb += NT) hist[bb] = v[c++];
        __syncthreads();
    }
    for (int bb = t; bb < 256; bb += NT) {
        int Sb  = m2 + (int)hist[bb];
        int Sb1 = m2 + (int)((bb < 255) ? hist[bb + 1] : 0u);
        if (Sb >= PRE_NMS && Sb1 < PRE_NMS) {
            sM3   = m2 + (int)((bb < 255) ? hist[bb + 1] : 0u);
            sNeed = PRE_NMS - sM3;
            sT32  = (P24 << 8) | (u32)bb;
        }
    }
    if (t == 0) { cHi = 0; cTie = 0; meta[0] = (V < PRE_NMS) ? V : PRE_NMS; }
    __syncthreads();
    int m3 = sM3, need = sNeed;
    u32 T32 = sT32;

    // ---- compaction -> global list[0..5999]; pad 6000..8191 with 0 ----
    for (int i = t; i < NA; i += NT) {
        u32 key = fkey(score[i]);
        u64 comp = ((u64)key << 32) | (u64)(0xFFFFFFFFu - (u32)i);
        if (key > T32) {
            int p = atomicAdd(&cHi, 1);
            list[p] = comp;
        } else if (key == T32) {
            int p = atomicAdd(&cTie, 1);
            if (p < need) list[m3 + p] = comp;
        }
    }
    for (int i = PRE_NMS + t; i < 8192; i += NT) list[i] = 0ull;
}

// =================== presort: 8 blocks each bitonic-sort a 1024-chunk (k=2..1024) ===================
__global__ __launch_bounds__(1024) void k_presort(u64* __restrict__ list) {
    __shared__ u64 ls[1024];
    int t  = threadIdx.x;
    int gi = (blockIdx.x << 10) + t;
    ls[t] = list[gi];
    __syncthreads();
    for (int k = 2; k <= 1024; k <<= 1) {
        for (int j = k >> 1; j > 0; j >>= 1) {
            int ixj = t ^ j;
            if (ixj > t) {
                u64 a = ls[t], b = ls[ixj];
                bool desc = ((gi & k) == 0);
                if (desc ? (a < b) : (a > b)) { ls[t] = b; ls[ixj] = a; }
            }
            __syncthreads();
        }
    }
    list[gi] = ls[t];
}

// =================== merge (k=2048..8192) + greedy NMS with killmask matrix ===================
__global__ __launch_bounds__(1024) void k_mergenms(const u64* __restrict__ list,
                                                   const float* __restrict__ boxes,
                                                   const int* __restrict__ meta,
                                                   float* __restrict__ rois) {
    __shared__ u64 sb[8192];
    __shared__ float kb[POST_NMS][4];
    __shared__ float cb4[64][4];
    __shared__ u32 KLo[64], KHi[64], supA[64];
    __shared__ int sKept;
    int t = threadIdx.x;
    const int NT = 1024;

    for (int i = t; i < 8192; i += NT) sb[i] = list[i];
    __syncthreads();

    // remaining bitonic phases
    for (int k = 2048; k <= 8192; k <<= 1) {
        for (int j = k >> 1; j > 0; j >>= 1) {
            for (int i = t; i < 8192; i += NT) {
                int ixj = i ^ j;
                if (ixj > i) {
                    u64 a = sb[i], bv = sb[ixj];
                    bool desc = ((i & k) == 0);
                    if (desc ? (a < bv) : (a > bv)) { sb[i] = bv; sb[ixj] = a; }
                }
            }
            __syncthreads();
        }
    }

    int keepN = meta[0];
    if (t == 0) sKept = 0;
    __syncthreads();

    int s = t >> 4, g = t & 15;   // 64 cands x 16 groups
    for (int c0 = 0; c0 < PRE_NMS; c0 += 64) {
        if (sKept >= POST_NMS) break;
        // load 64 candidate boxes
        if (t < 64) {
            u32 bidx = 0xFFFFFFFFu - (u32)sb[c0 + t];
            if (bidx >= NA) bidx = 0;            // pad-safe
            float4 bx = *(const float4*)(boxes + (size_t)bidx * 4);
            cb4[t][0] = bx.x; cb4[t][1] = bx.y; cb4[t][2] = bx.z; cb4[t][3] = bx.w;
            KLo[t] = 0; KHi[t] = 0; supA[t] = 0;
        }
        __syncthreads();

        float y1 = cb4[s][0], x1 = cb4[s][1], y2 = cb4[s][2], x2 = cb4[s][3];
        float area = (y2 - y1) * (x2 - x1);

        // pairwise kill bits: this thread covers j = g*4 .. g*4+3 for cand s
        u32 klo = 0, khi = 0;
#pragma unroll
        for (int qq = 0; qq < 4; ++qq) {
            int j = g * 4 + qq;
            if (j > s) {
                float jy1 = cb4[j][0], jx1 = cb4[j][1], jy2 = cb4[j][2], jx2 = cb4[j][3];
                float yy1 = fmaxf(y1, jy1), xx1 = fmaxf(x1, jx1);
                float yy2 = fminf(y2, jy2), xx2 = fminf(x2, jx2);
                float inter = fmaxf(yy2 - yy1, 0.f) * fmaxf(xx2 - xx1, 0.f);
                float ja = (jy2 - jy1) * (jx2 - jx1);
                float iou = inter / (area + ja - inter + 1e-12f);
                if (iou > 0.7f) { if (j < 32) klo |= 1u << j; else khi |= 1u << (j - 32); }
            }
        }
        if (klo) atomicOr(&KLo[s], klo);
        if (khi) atomicOr(&KHi[s], khi);

        // phase A: cand s vs already-kept, split 16 ways
        int kept0 = sKept;
        bool supf = false;
        for (int jj = g; jj < kept0; jj += 16) {
            float ky1 = kb[jj][0], kx1 = kb[jj][1], ky2 = kb[jj][2], kx2 = kb[jj][3];
            float yy1 = fmaxf(ky1, y1), xx1 = fmaxf(kx1, x1);
            float yy2 = fminf(ky2, y2), xx2 = fminf(kx2, x2);
            float inter = fmaxf(yy2 - yy1, 0.f) * fmaxf(xx2 - xx1, 0.f);
            float karea = (ky2 - ky1) * (kx2 - kx1);
            float iou = inter / (karea + area - inter + 1e-12f);
            if (iou > 0.7f) { supf = true; break; }
        }
        if (supf) atomicOr(&supA[s], 1u);
        __syncthreads();

        // serial greedy over the chunk (LDS reads only, no wave ops)
        if (t == 0) {
            u64 supm = 0;
            int kept = sKept;
            for (int s2 = 0; s2 < 64 && kept < POST_NMS; ++s2) {
                if (c0 + s2 >= keepN) continue;
                if (supA[s2]) continue;
                if ((supm >> s2) & 1ull) continue;
                kb[kept][0] = cb4[s2][0]; kb[kept][1] = cb4[s2][1];
                kb[kept][2] = cb4[s2][2]; kb[kept][3] = cb4[s2][3];
                *(float4*)(rois + (size_t)kept * 4) =
                    make_float4(cb4[s2][0], cb4[s2][1], cb4[s2][2], cb4[s2][3]);
                kept++;
                supm |= ((u64)KHi[s2] << 32) | (u64)KLo[s2];
            }
            sKept = kept;
        }
        __syncthreads();
    }

    int kf = sKept;
    for (int r = kf * 4 + t; r < POST_NMS * 4; r += NT) rois[r] = 0.f;
}

// =================== launcher ===================
extern "C" void kernel_launch(void* const* d_in, const int* in_sizes, int n_in,
                              void* d_out, int out_size, void* d_ws, size_t ws_size,
                              hipStream_t stream) {
    const float* feat = (const float*)d_in[0];
    const float* Wc   = (const float*)d_in[1];
    const float* bc   = (const float*)d_in[2];
    const float* Wcls = (const float*)d_in[3];
    const float* bcls = (const float*)d_in[4];
    const float* Wreg = (const float*)d_in[5];
    const float* breg = (const float*)d_in[6];
    const void* pih   = d_in[7];
    const void* piw   = d_in[8];
    float* out = (float*)d_out;
    float* ws  = (float*)d_ws;

    u32* WP   = (u32*)(ws + WS_WP);
    u64* list = (u64*)(ws + WS_LIST);
    int* meta = (int*)(ws + WS_META);
    bool haveXP = (ws_size >= (size_t)WS_END * sizeof(float));
    u32* XP = haveXP ? (u32*)(ws + WS_XP) : nullptr;

    int prepItems = NW_ELEMS + (haveXP ? NX_ELEMS : 0);
    hipLaunchKernelGGL(k_prep, dim3((prepItems + 255) / 256), dim3(256), 0, stream, Wc, feat, WP, XP);
    hipLaunchKernelGGL(k_conv3, dim3(640), dim3(256), 0, stream, feat, XP, WP, bc, ws + WS_X);
    hipLaunchKernelGGL(k_heads, dim3(160), dim3(256), 0, stream, ws + WS_X, Wreg, breg, Wcls, bcls,
                       out, ws + WS_SCORE, ws + WS_BOX, pih, piw);
    hipLaunchKernelGGL(k_select, dim3(1), dim3(1024), 0, stream, ws + WS_SCORE, list, meta);
    hipLaunchKernelGGL(k_presort, dim3(8), dim3(1024), 0, stream, list);
    hipLaunchKernelGGL(k_mergenms, dim3(1), dim3(1024), 0, stream, list, ws + WS_BOX, meta, out + OUT_ROIS);
}